// Round 13
// baseline (154.632 us; speedup 1.0000x reference)
//
#include <hip/hip_runtime.h>
#include <hip/hip_bf16.h>
#include <stdint.h>

typedef __bf16 bf16_t;
typedef __bf16 bf16x4 __attribute__((ext_vector_type(4)));
typedef __bf16 bf16x8 __attribute__((ext_vector_type(8)));
typedef float  f32x4  __attribute__((ext_vector_type(4)));

#define DM    1024
#define NH    16
#define HD    64
#define SEQ   2048
#define BATCH 2
#define BS    (BATCH*SEQ)   // 4096
#define NQKV  (3*DM)        // 3072

#define GLOAD_LDS16(g, l) \
  __builtin_amdgcn_global_load_lds((const __attribute__((address_space(1))) void*)(g), \
                                   (__attribute__((address_space(3))) void*)(l), 16, 0, 0)

__device__ __forceinline__ f32x4 mfma16(bf16x8 a, bf16x8 b, f32x4 c) {
  return __builtin_amdgcn_mfma_f32_16x16x32_bf16(a, b, c, 0, 0, 0);
}

// ---------------- merged cast/copy + rope-table kernel ----------------
__global__ __launch_bounds__(256) void k_cast_all(
    const float* __restrict__ x,  const float* __restrict__ Wq,
    const float* __restrict__ Wk, const float* __restrict__ Wv,
    const float* __restrict__ Wo, const float* __restrict__ bq,
    const float* __restrict__ bk, const float* __restrict__ bv,
    bf16_t* __restrict__ xb, bf16_t* __restrict__ Wcat,
    bf16_t* __restrict__ Wob, float* __restrict__ bcat,
    float2* __restrict__ rt)
{
  const int bid = blockIdx.x, tid = threadIdx.x;
  if (bid >= 4099) {
    const int idx = (bid - 4099) * 256 + tid;   // SEQ*32 = 65536 entries
    const int s = idx >> 5, i = idx & 31;
    float inv = powf(10000.0f, -(float)(2 * i) / 64.0f);
    float ang = (float)s * inv;
    rt[idx] = make_float2(cosf(ang), sinf(ang));
    return;
  }
  if (bid >= 4096) {
    const int k = bid - 4096;
    const float* src = (k == 0) ? bq : (k == 1) ? bk : bv;
    *(float4*)&bcat[k * DM + tid * 4] = *(const float4*)&src[tid * 4];
    return;
  }
  const float* src; bf16_t* dst; int i;
  if (bid < 2048)      { src = x;  dst = xb;                i = bid * 2048 + tid * 8; }
  else if (bid < 2560) { src = Wq; dst = Wcat;              i = (bid - 2048) * 2048 + tid * 8; }
  else if (bid < 3072) { src = Wk; dst = Wcat + DM * DM;    i = (bid - 2560) * 2048 + tid * 8; }
  else if (bid < 3584) { src = Wv; dst = Wcat + 2 * DM * DM;i = (bid - 3072) * 2048 + tid * 8; }
  else                 { src = Wo; dst = Wob;               i = (bid - 3584) * 2048 + tid * 8; }
  float4 a = *(const float4*)(src + i);
  float4 b = *(const float4*)(src + i + 4);
  bf16x8 o;
  o[0] = (bf16_t)a.x; o[1] = (bf16_t)a.y; o[2] = (bf16_t)a.z; o[3] = (bf16_t)a.w;
  o[4] = (bf16_t)b.x; o[5] = (bf16_t)b.y; o[6] = (bf16_t)b.z; o[7] = (bf16_t)b.w;
  *(bf16x8*)(dst + i) = o;
}

// ---------------- Q/K projection GEMM (transposed output) + bias + RoPE ----------
__global__ __launch_bounds__(256) void k_gemm_qk(
    const bf16_t* __restrict__ A, const bf16_t* __restrict__ B,
    const float* __restrict__ bias, const float2* __restrict__ rt,
    bf16_t* __restrict__ Qo, bf16_t* __restrict__ Ko)
{
  const int K = DM;
  __shared__ __align__(16) bf16_t As[128 * 32];
  __shared__ __align__(16) bf16_t Bs[128 * 32];
  const int tid  = threadIdx.x;
  const int lane = tid & 63;
  const int wave = tid >> 6;
  const int wr = wave >> 1, wc = wave & 1;
  const int m0 = blockIdx.y * 128, n0 = blockIdx.x * 128;
  const int c16 = lane & 15, g = lane >> 4;

  f32x4 acc[4][4];
  #pragma unroll
  for (int i = 0; i < 4; ++i)
    #pragma unroll
    for (int j = 0; j < 4; ++j)
      #pragma unroll
      for (int e = 0; e < 4; ++e) acc[i][j][e] = 0.0f;

  const int srow = wave * 32;
  const int lrow = lane >> 2;
  const int lk   = (lane & 3) * 8;
  const bf16_t* ga0 = A + (size_t)(m0 + srow +      lrow) * K + lk;
  const bf16_t* ga1 = A + (size_t)(m0 + srow + 16 + lrow) * K + lk;
  const bf16_t* gb0 = B + (size_t)(n0 + srow +      lrow) * K + lk;
  const bf16_t* gb1 = B + (size_t)(n0 + srow + 16 + lrow) * K + lk;
  bf16_t* la0 = &As[(srow)      * 32];
  bf16_t* la1 = &As[(srow + 16) * 32];
  bf16_t* lb0 = &Bs[(srow)      * 32];
  bf16_t* lb1 = &Bs[(srow + 16) * 32];

  const bf16_t* pa = &As[(wr * 64 + c16) * 32 + g * 8];
  const bf16_t* pb = &Bs[(wc * 64 + c16) * 32 + g * 8];

  for (int kt = 0; kt < K; kt += 32) {
    GLOAD_LDS16(ga0 + kt, la0);
    GLOAD_LDS16(ga1 + kt, la1);
    GLOAD_LDS16(gb0 + kt, lb0);
    GLOAD_LDS16(gb1 + kt, lb1);
    __syncthreads();
    bf16x8 af[4], bfr[4];
    #pragma unroll
    for (int t = 0; t < 4; ++t) af[t]  = *(const bf16x8*)(pa + t * 16 * 32);
    #pragma unroll
    for (int t = 0; t < 4; ++t) bfr[t] = *(const bf16x8*)(pb + t * 16 * 32);
    #pragma unroll
    for (int i = 0; i < 4; ++i)
      #pragma unroll
      for (int j = 0; j < 4; ++j)
        acc[i][j] = mfma16(bfr[j], af[i], acc[i][j]);   // SWAPPED -> C^T layout
    __syncthreads();
  }

  const int region = n0 >> 10;                 // 0=Q, 1=K
  bf16_t* dst = region ? Ko : Qo;
  const float qs = region ? 1.0f : (0.125f * 1.44269504088896f);
  #pragma unroll
  for (int j = 0; j < 4; ++j) {
    const int nb = n0 + wc * 64 + j * 16 + (g << 2);   // n of e=0
    const float4 bv = *(const float4*)&bias[nb];
    const int h  = (nb >> 6) & 15;
    const int d0 = nb & 63;
    #pragma unroll
    for (int i = 0; i < 4; ++i) {
      const int m = m0 + wr * 64 + i * 16 + c16;
      const int s = m & 2047;
      const int bh = ((m >> 11) << 4) + h;
      const float4 cs = *(const float4*)&rt[(size_t)s * 32 + (d0 >> 1)];
      const float v0 = acc[i][j][0] + bv.x;
      const float v1 = acc[i][j][1] + bv.y;
      const float v2 = acc[i][j][2] + bv.z;
      const float v3 = acc[i][j][3] + bv.w;
      bf16x4 ov;
      ov[0] = (bf16_t)((v0 * cs.x - v1 * cs.y) * qs);
      ov[1] = (bf16_t)((v0 * cs.y + v1 * cs.x) * qs);
      ov[2] = (bf16_t)((v2 * cs.z - v3 * cs.w) * qs);
      ov[3] = (bf16_t)((v2 * cs.w + v3 * cs.z) * qs);
      *(bf16x4*)&dst[((size_t)bh * SEQ + s) * HD + d0] = ov;
    }
  }
}

// ---------------- V projection GEMM + bias + PERMUTED V^T write ----------------
// kv = 16u + 4g + r  ->  p = (u>>1)*32 + g*8 + (u&1)*4 + r  (within aligned 64).
// Each aligned 32-block is self-contained, so attention can consume 32-kv tiles.
__global__ __launch_bounds__(256) void k_gemm_v(
    const bf16_t* __restrict__ A, const bf16_t* __restrict__ B,
    const float* __restrict__ bias, bf16_t* __restrict__ Vt)
{
  const int K = DM;
  __shared__ __align__(16) bf16_t As[128 * 32];
  __shared__ __align__(16) bf16_t Bs[128 * 32];
  const int tid  = threadIdx.x;
  const int lane = tid & 63;
  const int wave = tid >> 6;
  const int wr = wave >> 1, wc = wave & 1;
  const int m0 = blockIdx.y * 128, n0 = blockIdx.x * 128;
  const int c16 = lane & 15, g = lane >> 4;

  f32x4 acc[4][4];
  #pragma unroll
  for (int i = 0; i < 4; ++i)
    #pragma unroll
    for (int j = 0; j < 4; ++j)
      #pragma unroll
      for (int e = 0; e < 4; ++e) acc[i][j][e] = 0.0f;

  const int srow = wave * 32;
  const int lrow = lane >> 2;
  const int lk   = (lane & 3) * 8;
  const bf16_t* ga0 = A + (size_t)(m0 + srow +      lrow) * K + lk;
  const bf16_t* ga1 = A + (size_t)(m0 + srow + 16 + lrow) * K + lk;
  const bf16_t* gb0 = B + (size_t)(n0 + srow +      lrow) * K + lk;
  const bf16_t* gb1 = B + (size_t)(n0 + srow + 16 + lrow) * K + lk;
  bf16_t* la0 = &As[(srow)      * 32];
  bf16_t* la1 = &As[(srow + 16) * 32];
  bf16_t* lb0 = &Bs[(srow)      * 32];
  bf16_t* lb1 = &Bs[(srow + 16) * 32];

  const bf16_t* pa = &As[(wr * 64 + c16) * 32 + g * 8];
  const bf16_t* pb = &Bs[(wc * 64 + c16) * 32 + g * 8];

  for (int kt = 0; kt < K; kt += 32) {
    GLOAD_LDS16(ga0 + kt, la0);
    GLOAD_LDS16(ga1 + kt, la1);
    GLOAD_LDS16(gb0 + kt, lb0);
    GLOAD_LDS16(gb1 + kt, lb1);
    __syncthreads();
    bf16x8 af[4], bfr[4];
    #pragma unroll
    for (int t = 0; t < 4; ++t) af[t]  = *(const bf16x8*)(pa + t * 16 * 32);
    #pragma unroll
    for (int t = 0; t < 4; ++t) bfr[t] = *(const bf16x8*)(pb + t * 16 * 32);
    #pragma unroll
    for (int i = 0; i < 4; ++i)
      #pragma unroll
      for (int j = 0; j < 4; ++j)
        acc[i][j] = mfma16(af[i], bfr[j], acc[i][j]);
    __syncthreads();
  }

  const int rbase = m0 + wr * 64 + (g << 2);
  const int cbase = n0 + wc * 64 + c16;
  #pragma unroll
  for (int j = 0; j < 4; ++j) {
    const int c = cbase + j * 16;
    const float bv = bias[c];
    const int h = (c >> 6) & 15;
    const int d = c & 63;
    #pragma unroll
    for (int i = 0; i < 4; ++i) {
      bf16x4 ov;
      #pragma unroll
      for (int e = 0; e < 4; ++e) ov[e] = (bf16_t)(acc[i][j][e] + bv);
      const int r0 = rbase + i * 16;
      const int bh = ((r0 >> 11) << 4) + h;
      const int s0 = r0 & 2047;
      const int u  = (s0 >> 4) & 3;
      const int p0 = (s0 & ~63) + ((u >> 1) << 5) + (g << 3) + ((u & 1) << 2);
      *(bf16x4*)&Vt[((size_t)bh * HD + d) * SEQ + p0] = ov;
    }
  }
}

// ---------------- output projection GEMM: 8 waves, 128x128 tile ----------------
__global__ __launch_bounds__(512) void k_gemm_out(
    const bf16_t* __restrict__ A, const bf16_t* __restrict__ B,
    const float* __restrict__ bias, float* __restrict__ C)
{
  const int K = DM, N = DM;
  __shared__ __align__(16) bf16_t As[128 * 32];
  __shared__ __align__(16) bf16_t Bs[128 * 32];
  const int tid  = threadIdx.x;
  const int lane = tid & 63;
  const int w    = tid >> 6;
  const int wr = w >> 2, wc = w & 3;
  const int m0 = blockIdx.y * 128, n0 = blockIdx.x * 128;
  const int c16 = lane & 15, g = lane >> 4;

  f32x4 acc[4][2];
  #pragma unroll
  for (int i = 0; i < 4; ++i)
    #pragma unroll
    for (int j = 0; j < 2; ++j)
      #pragma unroll
      for (int e = 0; e < 4; ++e) acc[i][j][e] = 0.0f;

  const int lrow = lane >> 2;
  const int lk   = (lane & 3) * 8;
  const bf16_t* ga = A + (size_t)(m0 + w * 16 + lrow) * K + lk;
  const bf16_t* gb = B + (size_t)(n0 + w * 16 + lrow) * K + lk;
  bf16_t* la = &As[(w * 16) * 32];
  bf16_t* lb = &Bs[(w * 16) * 32];

  const bf16_t* pa = &As[(wr * 64 + c16) * 32 + g * 8];
  const bf16_t* pb = &Bs[(wc * 32 + c16) * 32 + g * 8];

  for (int kt = 0; kt < K; kt += 32) {
    GLOAD_LDS16(ga + kt, la);
    GLOAD_LDS16(gb + kt, lb);
    __syncthreads();
    bf16x8 af[4], bfr[2];
    #pragma unroll
    for (int t = 0; t < 4; ++t) af[t]  = *(const bf16x8*)(pa + t * 16 * 32);
    #pragma unroll
    for (int t = 0; t < 2; ++t) bfr[t] = *(const bf16x8*)(pb + t * 16 * 32);
    #pragma unroll
    for (int i = 0; i < 4; ++i)
      #pragma unroll
      for (int j = 0; j < 2; ++j)
        acc[i][j] = mfma16(af[i], bfr[j], acc[i][j]);
    __syncthreads();
  }

  const int rbase = m0 + wr * 64 + (g << 2);
  const int cbase = n0 + wc * 32 + c16;
  #pragma unroll
  for (int j = 0; j < 2; ++j) {
    const int c = cbase + j * 16;
    const float bv = bias[c];
    #pragma unroll
    for (int i = 0; i < 4; ++i) {
      #pragma unroll
      for (int e = 0; e < 4; ++e) {
        const int r = rbase + i * 16 + e;
        C[(size_t)r * N + c] = acc[i][j][e] + bv;
      }
    }
  }
}

// ---------------- flash attention v2: 2048 blocks, kv-parity split, 8 waves/SIMD --
// Block = 32 q-rows (qt in [0,64)), 4 waves: w&1 = row group (16 rows), w>>1 = kv
// parity. KVBLK=32; wave computes tiles with t&1==parity from its FIXED buffer;
// all waves cooperatively stage every tile. LDS 16KB -> 8 blocks/CU = 32 waves/CU.
// V-tile rows are 64B (32 kv) => dblk (16 d-rows) stride = 16*32 = 512 ELEMENTS
// (r12 bug: 1024 read past the buffer -> NaN). Partials merged via online-softmax
// combine through LDS after the final barrier.
__global__ __launch_bounds__(256, 8) void k_attn(
    const bf16_t* __restrict__ Q, const bf16_t* __restrict__ K,
    const bf16_t* __restrict__ Vt, bf16_t* __restrict__ O)
{
  __shared__ __align__(16) unsigned char smem[16384];
  bf16_t* kb0 = (bf16_t*)smem;          // [2048] = 32 rows x 64 d (swizzled)
  bf16_t* kb1 = kb0 + 2048;
  bf16_t* vb0 = kb1 + 2048;             // [2048] = 64 d-rows x 32 kv (swizzled)
  bf16_t* vb1 = vb0 + 2048;

  const int tid = threadIdx.x, lane = tid & 63, w = tid >> 6;
  const int bh = blockIdx.x & 31;
  const int kk = (blockIdx.x >> 5) & 7;
  const int rr = blockIdx.x >> 8;                       // 0..7
  const int qt = rr * 8 + ((rr & 1) ? 7 - kk : kk);     // [0,64), const-sum
  const int b  = bh >> 4, h = bh & 15;
  const int rg = w & 1, par = w >> 1;
  const int q0 = qt * 32 + rg * 16;
  const int c16 = lane & 15, g = lane >> 4;
  const int q   = q0 + c16;

  const bf16_t* Qb = Q  + (size_t)bh * SEQ * HD;
  const bf16_t* Kb = K  + (size_t)bh * SEQ * HD;
  const bf16_t* Vb = Vt + (size_t)bh * HD * SEQ;

  bf16x8 qf0 = *(const bf16x8*)&Qb[(size_t)q * HD + g * 8];
  bf16x8 qf1 = *(const bf16x8*)&Qb[(size_t)q * HD + 32 + g * 8];

  f32x4 oacc[4];
  #pragma unroll
  for (int dblk = 0; dblk < 4; ++dblk)
    #pragma unroll
    for (int e = 0; e < 4; ++e) oacc[dblk][e] = 0.0f;
  float m_ = -1e30f, l_ = 0.0f;

  const int T = qt + 1;

  // ---- staging addresses (hoisted) ----
  const int soff  = w * 1024 + lane * 16;               // [0,4096) dest byte
  const int krow  = soff >> 7;                          // 0..31 (128B rows)
  const int kcolb = (soff & 127) ^ ((krow & 7) << 4);
  const int vrow  = soff >> 6;                          // 0..63 (64B rows)
  const int vcolb = (soff & 63) ^ (((vrow >> 1) & 3) << 4);
  const bf16_t* gk = &Kb[(size_t)krow * HD + (kcolb >> 1)];
  const bf16_t* gv = &Vb[(size_t)vrow * SEQ + (vcolb >> 1)];
  bf16_t* kD0 = kb0 + ((w * 1024) >> 1);
  bf16_t* kD1 = kb1 + ((w * 1024) >> 1);
  bf16_t* vD0 = vb0 + ((w * 1024) >> 1);
  bf16_t* vD1 = vb1 + ((w * 1024) >> 1);

  // ---- compute-side pointers (buffer fixed = par) ----
  const int e0  = ((16 * g) ^ ((c16 & 7) << 4)) >> 1;
  const int dhi = (((64 + 16 * g) ^ ((c16 & 7) << 4)) >> 1) - e0;  // = e0^32 delta
  const bf16_t* kp = (par ? kb1 : kb0) + c16 * 64 + e0;
  const int ve  = ((16 * g) ^ (((c16 >> 1) & 3) << 4)) >> 1;
  const bf16_t* vp = (par ? vb1 : vb0) + c16 * 32 + ve;

  GLOAD_LDS16(gk, kD0); GLOAD_LDS16(gv, vD0);
  gk += 32 * HD; gv += 32;
  __syncthreads();

  for (int t = 0; t < T; ++t) {
    if (t + 1 < T) {
      const bool nb = (t + 1) & 1;
      GLOAD_LDS16(gk, nb ? kD1 : kD0);
      GLOAD_LDS16(gv, nb ? vD1 : vD0);
      gk += 32 * HD; gv += 32;
    }

    if ((t & 1) == par) {
      // ---- QK^T (swapped): st[u][r] = S[32t+16u+4g+r][q] ----
      f32x4 st[2];
      __builtin_amdgcn_s_setprio(1);
      #pragma unroll
      for (int u = 0; u < 2; ++u) {
        bf16x8 k0 = *(const bf16x8*)(kp + u * 1024);
        bf16x8 k1 = *(const bf16x8*)(kp + u * 1024 + dhi);
        f32x4 z; z[0] = z[1] = z[2] = z[3] = 0.0f;
        z = mfma16(k0, qf0, z);
        z = mfma16(k1, qf1, z);
        st[u] = z;
      }
      __builtin_amdgcn_s_setprio(0);

      // ---- V fragments (permuted layout; 64B rows -> dblk stride 512 elems) ----
      bf16x8 vf[4];
      #pragma unroll
      for (int dblk = 0; dblk < 4; ++dblk)
        vf[dblk] = *(const bf16x8*)(vp + dblk * 512);

      // ---- mask (scale folded into Q); only the diagonal tile compares ----
      float pv[8];
      if (t == qt) {
        const int kv0 = t * 32;
        #pragma unroll
        for (int u = 0; u < 2; ++u)
          #pragma unroll
          for (int r = 0; r < 4; ++r) {
            const int kv = kv0 + 16 * u + 4 * g + r;
            pv[u * 4 + r] = (kv <= q) ? st[u][r] : -1e30f;
          }
      } else {
        #pragma unroll
        for (int u = 0; u < 2; ++u)
          #pragma unroll
          for (int r = 0; r < 4; ++r)
            pv[u * 4 + r] = st[u][r];
      }

      // ---- local 8-max (no cross-lane in common path) ----
      float ma = fmaxf(fmaxf(pv[0], pv[1]), fmaxf(pv[2], pv[3]));
      float mb = fmaxf(fmaxf(pv[4], pv[5]), fmaxf(pv[6], pv[7]));
      const float lmx = fmaxf(ma, mb);

      if (__any(lmx - m_ > 12.0f)) {
        float mx = fmaxf(lmx, __shfl_xor(lmx, 16));
        mx = fmaxf(mx, __shfl_xor(mx, 32));
        const float mn = fmaxf(m_, mx);
        const float alpha = exp2f(m_ - mn);
        l_ *= alpha;
        #pragma unroll
        for (int dblk = 0; dblk < 4; ++dblk)
          #pragma unroll
          for (int e = 0; e < 4; ++e) oacc[dblk][e] *= alpha;
        m_ = mn;
      }

      // ---- exp + per-lane partial sum ----
      #pragma unroll
      for (int i = 0; i < 8; ++i) pv[i] = exp2f(pv[i] - m_);
      l_ += ((pv[0] + pv[1]) + (pv[2] + pv[3])) + ((pv[4] + pv[5]) + (pv[6] + pv[7]));

      bf16x8 pf0;
      #pragma unroll
      for (int j = 0; j < 8; ++j) pf0[j] = (bf16_t)pv[j];

      // ---- PV ----
      __builtin_amdgcn_s_setprio(1);
      #pragma unroll
      for (int dblk = 0; dblk < 4; ++dblk)
        oacc[dblk] = mfma16(vf[dblk], pf0, oacc[dblk]);
      __builtin_amdgcn_s_setprio(0);
    }

    __syncthreads();
  }

  // ---- combine parity partials (online-softmax merge) ----
  float* comb = (float*)smem;   // [2][64][18], reuse of K/V buffers
  if (par == 1) {
    float* cpd = comb + (rg * 64 + lane) * 18;
    cpd[0] = m_; cpd[1] = l_;
    #pragma unroll
    for (int dblk = 0; dblk < 4; ++dblk)
      #pragma unroll
      for (int e = 0; e < 4; ++e) cpd[2 + dblk * 4 + e] = oacc[dblk][e];
  }
  __syncthreads();
  if (par == 0) {
    const float* cps = comb + (rg * 64 + lane) * 18;
    const float m2 = cps[0], l2 = cps[1];
    const float M  = fmaxf(m_, m2);
    const float a1 = exp2f(m_ - M);
    const float a2 = exp2f(m2 - M);
    float l = a1 * l_ + a2 * l2;
    l += __shfl_xor(l, 16);
    l += __shfl_xor(l, 32);
    const float inv = 1.0f / l;
    bf16_t* orow = O + ((size_t)(b * SEQ + q)) * DM + h * HD;
    #pragma unroll
    for (int dblk = 0; dblk < 4; ++dblk) {
      bf16x4 ov;
      #pragma unroll
      for (int r = 0; r < 4; ++r)
        ov[r] = (bf16_t)((a1 * oacc[dblk][r] + a2 * cps[2 + dblk * 4 + r]) * inv);
      *(bf16x4*)&orow[dblk * 16 + 4 * g] = ov;
    }
  }
}

// ---------------- launch ----------------
extern "C" void kernel_launch(void* const* d_in, const int* in_sizes, int n_in,
                              void* d_out, int out_size, void* d_ws, size_t ws_size,
                              hipStream_t stream)
{
  const float* x  = (const float*)d_in[0];
  const float* Wq = (const float*)d_in[1];
  const float* bq = (const float*)d_in[2];
  const float* Wk = (const float*)d_in[3];
  const float* bk = (const float*)d_in[4];
  const float* Wv = (const float*)d_in[5];
  const float* bv = (const float*)d_in[6];
  const float* Wo = (const float*)d_in[7];
  const float* bo = (const float*)d_in[8];
  float* out = (float*)d_out;

  char* ws = (char*)d_ws;
  size_t off = 0;
  auto alloc = [&](size_t bytes) { char* p = ws + off; off += (bytes + 255) & ~255ULL; return p; };
  bf16_t* xb   = (bf16_t*)alloc((size_t)BS * DM * 2);
  bf16_t* Wcat = (bf16_t*)alloc((size_t)NQKV * DM * 2);
  bf16_t* Wob  = (bf16_t*)alloc((size_t)DM * DM * 2);
  float*  bcat = (float*)alloc((size_t)NQKV * 4);
  float2* rt   = (float2*)alloc((size_t)SEQ * 32 * 8);
  bf16_t* Qh   = (bf16_t*)alloc((size_t)BS * DM * 2);
  bf16_t* Kh   = (bf16_t*)alloc((size_t)BS * DM * 2);
  bf16_t* Vth  = (bf16_t*)alloc((size_t)BS * DM * 2);
  bf16_t* Oh   = (bf16_t*)alloc((size_t)BS * DM * 2);
  (void)ws_size; (void)in_sizes; (void)n_in; (void)out_size;

  k_cast_all<<<4099 + 256, 256, 0, stream>>>(x, Wq, Wk, Wv, Wo, bq, bk, bv,
                                             xb, Wcat, Wob, bcat, rt);

  dim3 gqk(16, 32);
  k_gemm_qk<<<gqk, 256, 0, stream>>>(xb, Wcat, bcat, rt, Qh, Kh);
  dim3 gv(8, 32);
  k_gemm_v<<<gv, 256, 0, stream>>>(xb, Wcat + 2 * DM * DM, bcat + 2 * DM, Vth);
  k_attn<<<2048, 256, 0, stream>>>(Qh, Kh, Vth, Oh);
  dim3 g2(DM / 128, BS / 128);
  k_gemm_out<<<g2, 512, 0, stream>>>(Oh, Wob, bo, out);
}

// Round 14
// 139.945 us; speedup vs baseline: 1.1049x; 1.1049x over previous
//
#include <hip/hip_runtime.h>
#include <hip/hip_bf16.h>
#include <stdint.h>

typedef __bf16 bf16_t;
typedef __bf16 bf16x4 __attribute__((ext_vector_type(4)));
typedef __bf16 bf16x8 __attribute__((ext_vector_type(8)));
typedef float  f32x4  __attribute__((ext_vector_type(4)));

#define DM    1024
#define NH    16
#define HD    64
#define SEQ   2048
#define BATCH 2
#define BS    (BATCH*SEQ)   // 4096
#define NQKV  (3*DM)        // 3072

#define GLOAD_LDS16(g, l) \
  __builtin_amdgcn_global_load_lds((const __attribute__((address_space(1))) void*)(g), \
                                   (__attribute__((address_space(3))) void*)(l), 16, 0, 0)

__device__ __forceinline__ f32x4 mfma16(bf16x8 a, bf16x8 b, f32x4 c) {
  return __builtin_amdgcn_mfma_f32_16x16x32_bf16(a, b, c, 0, 0, 0);
}

// ---------------- merged cast/copy + rope-table kernel ----------------
__global__ __launch_bounds__(256) void k_cast_all(
    const float* __restrict__ x,  const float* __restrict__ Wq,
    const float* __restrict__ Wk, const float* __restrict__ Wv,
    const float* __restrict__ Wo, const float* __restrict__ bq,
    const float* __restrict__ bk, const float* __restrict__ bv,
    bf16_t* __restrict__ xb, bf16_t* __restrict__ Wcat,
    bf16_t* __restrict__ Wob, float* __restrict__ bcat,
    float2* __restrict__ rt)
{
  const int bid = blockIdx.x, tid = threadIdx.x;
  if (bid >= 4099) {
    const int idx = (bid - 4099) * 256 + tid;   // SEQ*32 = 65536 entries
    const int s = idx >> 5, i = idx & 31;
    float inv = powf(10000.0f, -(float)(2 * i) / 64.0f);
    float ang = (float)s * inv;
    rt[idx] = make_float2(cosf(ang), sinf(ang));
    return;
  }
  if (bid >= 4096) {
    const int k = bid - 4096;
    const float* src = (k == 0) ? bq : (k == 1) ? bk : bv;
    *(float4*)&bcat[k * DM + tid * 4] = *(const float4*)&src[tid * 4];
    return;
  }
  const float* src; bf16_t* dst; int i;
  if (bid < 2048)      { src = x;  dst = xb;                i = bid * 2048 + tid * 8; }
  else if (bid < 2560) { src = Wq; dst = Wcat;              i = (bid - 2048) * 2048 + tid * 8; }
  else if (bid < 3072) { src = Wk; dst = Wcat + DM * DM;    i = (bid - 2560) * 2048 + tid * 8; }
  else if (bid < 3584) { src = Wv; dst = Wcat + 2 * DM * DM;i = (bid - 3072) * 2048 + tid * 8; }
  else                 { src = Wo; dst = Wob;               i = (bid - 3584) * 2048 + tid * 8; }
  float4 a = *(const float4*)(src + i);
  float4 b = *(const float4*)(src + i + 4);
  bf16x8 o;
  o[0] = (bf16_t)a.x; o[1] = (bf16_t)a.y; o[2] = (bf16_t)a.z; o[3] = (bf16_t)a.w;
  o[4] = (bf16_t)b.x; o[5] = (bf16_t)b.y; o[6] = (bf16_t)b.z; o[7] = (bf16_t)b.w;
  *(bf16x8*)(dst + i) = o;
}

// ---------------- merged QKV projection GEMM + bias + RoPE / V^T ----------------
// grid (24, 32): n0 = bx*128 in [0,3072), region = n0>>10 (0=Q,1=K,2=V).
// Q/K regions: C^T via mfma(bfr, af); RoPE pairs lane-local; bf16x4 stores.
// V region: normal mfma; permuted V^T write (kv = 16u+4g+r -> p, see below).
__global__ __launch_bounds__(256) void k_gemm_qkv(
    const bf16_t* __restrict__ A, const bf16_t* __restrict__ B,
    const float* __restrict__ bias, const float2* __restrict__ rt,
    bf16_t* __restrict__ Qo, bf16_t* __restrict__ Ko, bf16_t* __restrict__ Vt)
{
  const int K = DM;
  __shared__ __align__(16) bf16_t As[128 * 32];
  __shared__ __align__(16) bf16_t Bs[128 * 32];
  const int tid  = threadIdx.x;
  const int lane = tid & 63;
  const int wave = tid >> 6;
  const int wr = wave >> 1, wc = wave & 1;
  const int m0 = blockIdx.y * 128, n0 = blockIdx.x * 128;
  const int c16 = lane & 15, g = lane >> 4;
  const int region = n0 >> 10;                 // 0=Q, 1=K, 2=V

  f32x4 acc[4][4];
  #pragma unroll
  for (int i = 0; i < 4; ++i)
    #pragma unroll
    for (int j = 0; j < 4; ++j)
      #pragma unroll
      for (int e = 0; e < 4; ++e) acc[i][j][e] = 0.0f;

  const int srow = wave * 32;
  const int lrow = lane >> 2;
  const int lk   = (lane & 3) * 8;
  const bf16_t* ga0 = A + (size_t)(m0 + srow +      lrow) * K + lk;
  const bf16_t* ga1 = A + (size_t)(m0 + srow + 16 + lrow) * K + lk;
  const bf16_t* gb0 = B + (size_t)(n0 + srow +      lrow) * K + lk;
  const bf16_t* gb1 = B + (size_t)(n0 + srow + 16 + lrow) * K + lk;
  bf16_t* la0 = &As[(srow)      * 32];
  bf16_t* la1 = &As[(srow + 16) * 32];
  bf16_t* lb0 = &Bs[(srow)      * 32];
  bf16_t* lb1 = &Bs[(srow + 16) * 32];

  const bf16_t* pa = &As[(wr * 64 + c16) * 32 + g * 8];
  const bf16_t* pb = &Bs[(wc * 64 + c16) * 32 + g * 8];

  for (int kt = 0; kt < K; kt += 32) {
    GLOAD_LDS16(ga0 + kt, la0);
    GLOAD_LDS16(ga1 + kt, la1);
    GLOAD_LDS16(gb0 + kt, lb0);
    GLOAD_LDS16(gb1 + kt, lb1);
    __syncthreads();
    bf16x8 af[4], bfr[4];
    #pragma unroll
    for (int t = 0; t < 4; ++t) af[t]  = *(const bf16x8*)(pa + t * 16 * 32);
    #pragma unroll
    for (int t = 0; t < 4; ++t) bfr[t] = *(const bf16x8*)(pb + t * 16 * 32);
    if (region < 2) {
      #pragma unroll
      for (int i = 0; i < 4; ++i)
        #pragma unroll
        for (int j = 0; j < 4; ++j)
          acc[i][j] = mfma16(bfr[j], af[i], acc[i][j]);   // SWAPPED -> C^T
    } else {
      #pragma unroll
      for (int i = 0; i < 4; ++i)
        #pragma unroll
        for (int j = 0; j < 4; ++j)
          acc[i][j] = mfma16(af[i], bfr[j], acc[i][j]);   // normal
    }
    __syncthreads();
  }

  if (region < 2) {
    bf16_t* dst = region ? Ko : Qo;
    const float qs = region ? 1.0f : (0.125f * 1.44269504088896f);
    #pragma unroll
    for (int j = 0; j < 4; ++j) {
      const int nb = n0 + wc * 64 + j * 16 + (g << 2);   // n of e=0
      const float4 bv = *(const float4*)&bias[nb];
      const int h  = (nb >> 6) & 15;
      const int d0 = nb & 63;
      #pragma unroll
      for (int i = 0; i < 4; ++i) {
        const int m = m0 + wr * 64 + i * 16 + c16;
        const int s = m & 2047;
        const int bh = ((m >> 11) << 4) + h;
        const float4 cs = *(const float4*)&rt[(size_t)s * 32 + (d0 >> 1)];
        const float v0 = acc[i][j][0] + bv.x;
        const float v1 = acc[i][j][1] + bv.y;
        const float v2 = acc[i][j][2] + bv.z;
        const float v3 = acc[i][j][3] + bv.w;
        bf16x4 ov;
        ov[0] = (bf16_t)((v0 * cs.x - v1 * cs.y) * qs);
        ov[1] = (bf16_t)((v0 * cs.y + v1 * cs.x) * qs);
        ov[2] = (bf16_t)((v2 * cs.z - v3 * cs.w) * qs);
        ov[3] = (bf16_t)((v2 * cs.w + v3 * cs.z) * qs);
        *(bf16x4*)&dst[((size_t)bh * SEQ + s) * HD + d0] = ov;
      }
    }
  } else {
    const int rbase = m0 + wr * 64 + (g << 2);
    const int cbase = n0 + wc * 64 + c16;
    #pragma unroll
    for (int j = 0; j < 4; ++j) {
      const int c = cbase + j * 16;
      const float bv = bias[c];
      const int h = (c >> 6) & 15;
      const int d = c & 63;
      #pragma unroll
      for (int i = 0; i < 4; ++i) {
        bf16x4 ov;
        #pragma unroll
        for (int e = 0; e < 4; ++e) ov[e] = (bf16_t)(acc[i][j][e] + bv);
        const int r0 = rbase + i * 16;
        const int bh = ((r0 >> 11) << 4) + h;
        const int s0 = r0 & 2047;
        const int u  = (s0 >> 4) & 3;
        const int p0 = (s0 & ~63) + ((u >> 1) << 5) + (g << 3) + ((u & 1) << 2);
        *(bf16x4*)&Vt[((size_t)bh * HD + d) * SEQ + p0] = ov;
      }
    }
  }
}

// ---------------- output projection GEMM: 8 waves, 128x128 tile ----------------
__global__ __launch_bounds__(512) void k_gemm_out(
    const bf16_t* __restrict__ A, const bf16_t* __restrict__ B,
    const float* __restrict__ bias, float* __restrict__ C)
{
  const int K = DM, N = DM;
  __shared__ __align__(16) bf16_t As[128 * 32];
  __shared__ __align__(16) bf16_t Bs[128 * 32];
  const int tid  = threadIdx.x;
  const int lane = tid & 63;
  const int w    = tid >> 6;
  const int wr = w >> 2, wc = w & 3;
  const int m0 = blockIdx.y * 128, n0 = blockIdx.x * 128;
  const int c16 = lane & 15, g = lane >> 4;

  f32x4 acc[4][2];
  #pragma unroll
  for (int i = 0; i < 4; ++i)
    #pragma unroll
    for (int j = 0; j < 2; ++j)
      #pragma unroll
      for (int e = 0; e < 4; ++e) acc[i][j][e] = 0.0f;

  const int lrow = lane >> 2;
  const int lk   = (lane & 3) * 8;
  const bf16_t* ga = A + (size_t)(m0 + w * 16 + lrow) * K + lk;
  const bf16_t* gb = B + (size_t)(n0 + w * 16 + lrow) * K + lk;
  bf16_t* la = &As[(w * 16) * 32];
  bf16_t* lb = &Bs[(w * 16) * 32];

  const bf16_t* pa = &As[(wr * 64 + c16) * 32 + g * 8];
  const bf16_t* pb = &Bs[(wc * 32 + c16) * 32 + g * 8];

  for (int kt = 0; kt < K; kt += 32) {
    GLOAD_LDS16(ga + kt, la);
    GLOAD_LDS16(gb + kt, lb);
    __syncthreads();
    bf16x8 af[4], bfr[2];
    #pragma unroll
    for (int t = 0; t < 4; ++t) af[t]  = *(const bf16x8*)(pa + t * 16 * 32);
    #pragma unroll
    for (int t = 0; t < 2; ++t) bfr[t] = *(const bf16x8*)(pb + t * 16 * 32);
    #pragma unroll
    for (int i = 0; i < 4; ++i)
      #pragma unroll
      for (int j = 0; j < 2; ++j)
        acc[i][j] = mfma16(af[i], bfr[j], acc[i][j]);
    __syncthreads();
  }

  const int rbase = m0 + wr * 64 + (g << 2);
  const int cbase = n0 + wc * 32 + c16;
  #pragma unroll
  for (int j = 0; j < 2; ++j) {
    const int c = cbase + j * 16;
    const float bv = bias[c];
    #pragma unroll
    for (int i = 0; i < 4; ++i) {
      #pragma unroll
      for (int e = 0; e < 4; ++e) {
        const int r = rbase + i * 16 + e;
        C[(size_t)r * N + c] = acc[i][j][e] + bv;
      }
    }
  }
}

// ---------------- flash attention (r11 version, 44 us measured) ----------------
// 4-wave / 64-row blocks, P in registers, permuted-V b128 reads (0 conflicts),
// constant-sum block->(qt,bh) mapping, local-max defer trigger, deferred l-reduce.
__global__ __launch_bounds__(256, 4) void k_attn(
    const bf16_t* __restrict__ Q, const bf16_t* __restrict__ K,
    const bf16_t* __restrict__ Vt, bf16_t* __restrict__ O)
{
  __shared__ __align__(16) bf16_t kbuf[2][64 * 64];
  __shared__ __align__(16) bf16_t vbuf[2][64 * 64];
  const int tid = threadIdx.x, lane = tid & 63, w = tid >> 6;
  const int rr = blockIdx.x >> 8;          // 0..3
  const int kk = (blockIdx.x >> 5) & 7;    // 0..7
  const int bh = blockIdx.x & 31;
  const int qt = (rr == 0) ? kk : (rr == 1) ? 15 - kk : (rr == 2) ? 16 + kk : 31 - kk;
  const int b  = bh >> 4, h = bh & 15;
  const int q0 = qt * 64 + w * 16;
  const int c16 = lane & 15;
  const int g   = lane >> 4;
  const int q   = q0 + c16;

  const bf16_t* Qb = Q  + (size_t)bh * SEQ * HD;
  const bf16_t* Kb = K  + (size_t)bh * SEQ * HD;
  const bf16_t* Vb = Vt + (size_t)bh * HD * SEQ;

  bf16x8 qf0 = *(const bf16x8*)&Qb[(size_t)q * HD + g * 8];
  bf16x8 qf1 = *(const bf16x8*)&Qb[(size_t)q * HD + 32 + g * 8];

  f32x4 oacc[4];
  #pragma unroll
  for (int dblk = 0; dblk < 4; ++dblk)
    #pragma unroll
    for (int e = 0; e < 4; ++e) oacc[dblk][e] = 0.0f;
  float m_ = -1e30f, l_ = 0.0f;

  const int ntile = qt + 1;

  const int soff0 = w * 1024 + lane * 16;
  const int soff1 = soff0 + 4096;
  const int srow0 = soff0 >> 7, srow1 = soff1 >> 7;
  const int scb0  = (soff0 & 127) ^ ((srow0 & 7) << 4);
  const int scb1  = (soff1 & 127) ^ ((srow1 & 7) << 4);
  const bf16_t* gk0 = &Kb[(size_t)srow0 * HD + (scb0 >> 1)];
  const bf16_t* gk1 = &Kb[(size_t)srow1 * HD + (scb1 >> 1)];
  const bf16_t* gv0 = &Vb[(size_t)srow0 * SEQ + (scb0 >> 1)];
  const bf16_t* gv1 = &Vb[(size_t)srow1 * SEQ + (scb1 >> 1)];
  bf16_t* lk0A = &kbuf[0][(w * 1024) >> 1];
  bf16_t* lk1A = &kbuf[0][(w * 1024 + 4096) >> 1];
  bf16_t* lk0B = &kbuf[1][(w * 1024) >> 1];
  bf16_t* lk1B = &kbuf[1][(w * 1024 + 4096) >> 1];
  bf16_t* lv0A = &vbuf[0][(w * 1024) >> 1];
  bf16_t* lv1A = &vbuf[0][(w * 1024 + 4096) >> 1];
  bf16_t* lv0B = &vbuf[1][(w * 1024) >> 1];
  bf16_t* lv1B = &vbuf[1][(w * 1024 + 4096) >> 1];

  const int sw = (c16 & 7) << 4;
  const int e0 = ((16 * g) ^ sw) >> 1;
  const int dhi = (((64 + 16 * g) ^ sw) >> 1) - e0;
  const bf16_t* kp0 = &kbuf[0][c16 * 64 + e0];
  const bf16_t* kp1 = &kbuf[1][c16 * 64 + e0];
  const bf16_t* vp0 = &vbuf[0][c16 * 64 + e0];
  const bf16_t* vp1 = &vbuf[1][c16 * 64 + e0];

  GLOAD_LDS16(gk0, lk0A); GLOAD_LDS16(gk1, lk1A);
  GLOAD_LDS16(gv0, lv0A); GLOAD_LDS16(gv1, lv1A);
  gk0 += 4096; gk1 += 4096; gv0 += 64; gv1 += 64;
  __syncthreads();

  for (int t = 0; t < ntile; ++t) {
    const bool odd = t & 1;
    if (t + 1 < ntile) {
      GLOAD_LDS16(gk0, odd ? lk0A : lk0B); GLOAD_LDS16(gk1, odd ? lk1A : lk1B);
      GLOAD_LDS16(gv0, odd ? lv0A : lv0B); GLOAD_LDS16(gv1, odd ? lv1A : lv1B);
      gk0 += 4096; gk1 += 4096; gv0 += 64; gv1 += 64;
    }

    const bf16_t* kp = odd ? kp1 : kp0;
    const bf16_t* vp = odd ? vp1 : vp0;

    f32x4 st[4];
    __builtin_amdgcn_s_setprio(1);
    #pragma unroll
    for (int u = 0; u < 4; ++u) {
      bf16x8 k0 = *(const bf16x8*)(kp + u * 1024);
      bf16x8 k1 = *(const bf16x8*)(kp + u * 1024 + dhi);
      f32x4 z; z[0] = z[1] = z[2] = z[3] = 0.0f;
      z = mfma16(k0, qf0, z);
      z = mfma16(k1, qf1, z);
      st[u] = z;
    }
    __builtin_amdgcn_s_setprio(0);

    // ---- V fragments: b128 swizzled reads (permuted layout), same as K ----
    bf16x8 vlo[4], vhi[4];
    #pragma unroll
    for (int dblk = 0; dblk < 4; ++dblk) {
      vlo[dblk] = *(const bf16x8*)(vp + dblk * 1024);
      vhi[dblk] = *(const bf16x8*)(vp + dblk * 1024 + dhi);
    }

    float pv[16];
    if (t == qt) {
      const int kv0 = t * 64;
      #pragma unroll
      for (int u = 0; u < 4; ++u)
        #pragma unroll
        for (int r = 0; r < 4; ++r) {
          const int kv = kv0 + 16 * u + 4 * g + r;
          pv[u * 4 + r] = (kv <= q) ? st[u][r] : -1e30f;
        }
    } else {
      #pragma unroll
      for (int u = 0; u < 4; ++u)
        #pragma unroll
        for (int r = 0; r < 4; ++r)
          pv[u * 4 + r] = st[u][r];
    }

    // ---- local 16-max only (no cross-lane in common path) ----
    float ma = fmaxf(fmaxf(pv[0], pv[1]), fmaxf(pv[2], pv[3]));
    float mb = fmaxf(fmaxf(pv[4], pv[5]), fmaxf(pv[6], pv[7]));
    float mc = fmaxf(fmaxf(pv[8], pv[9]), fmaxf(pv[10], pv[11]));
    float md = fmaxf(fmaxf(pv[12], pv[13]), fmaxf(pv[14], pv[15]));
    const float lmx = fmaxf(fmaxf(ma, mb), fmaxf(mc, md));

    if (__any(lmx - m_ > 12.0f)) {
      float mx = fmaxf(lmx, __shfl_xor(lmx, 16));
      mx = fmaxf(mx, __shfl_xor(mx, 32));
      const float mn = fmaxf(m_, mx);
      const float alpha = exp2f(m_ - mn);
      l_ *= alpha;
      #pragma unroll
      for (int dblk = 0; dblk < 4; ++dblk)
        #pragma unroll
        for (int e = 0; e < 4; ++e) oacc[dblk][e] *= alpha;
      m_ = mn;
    }

    #pragma unroll
    for (int i = 0; i < 16; ++i) pv[i] = exp2f(pv[i] - m_);
    float s0 = (pv[0] + pv[1]) + (pv[2] + pv[3]);
    float s1 = (pv[4] + pv[5]) + (pv[6] + pv[7]);
    float s2 = (pv[8] + pv[9]) + (pv[10] + pv[11]);
    float s3 = (pv[12] + pv[13]) + (pv[14] + pv[15]);
    l_ += (s0 + s1) + (s2 + s3);

    bf16x8 pf0, pf1;
    #pragma unroll
    for (int j = 0; j < 8; ++j) {
      pf0[j] = (bf16_t)pv[j];
      pf1[j] = (bf16_t)pv[8 + j];
    }

    __builtin_amdgcn_s_setprio(1);
    #pragma unroll
    for (int dblk = 0; dblk < 4; ++dblk) {
      oacc[dblk] = mfma16(vlo[dblk], pf0, oacc[dblk]);
      oacc[dblk] = mfma16(vhi[dblk], pf1, oacc[dblk]);
    }
    __builtin_amdgcn_s_setprio(0);

    __syncthreads();
  }

  l_ += __shfl_xor(l_, 16);
  l_ += __shfl_xor(l_, 32);
  const float inv = 1.0f / l_;
  bf16_t* orow = O + ((size_t)(b * SEQ + q)) * DM + h * HD;
  #pragma unroll
  for (int dblk = 0; dblk < 4; ++dblk) {
    bf16x4 ov;
    #pragma unroll
    for (int r = 0; r < 4; ++r) ov[r] = (bf16_t)(oacc[dblk][r] * inv);
    *(bf16x4*)&orow[dblk * 16 + 4 * g] = ov;
  }
}

// ---------------- launch ----------------
extern "C" void kernel_launch(void* const* d_in, const int* in_sizes, int n_in,
                              void* d_out, int out_size, void* d_ws, size_t ws_size,
                              hipStream_t stream)
{
  const float* x  = (const float*)d_in[0];
  const float* Wq = (const float*)d_in[1];
  const float* bq = (const float*)d_in[2];
  const float* Wk = (const float*)d_in[3];
  const float* bk = (const float*)d_in[4];
  const float* Wv = (const float*)d_in[5];
  const float* bv = (const float*)d_in[6];
  const float* Wo = (const float*)d_in[7];
  const float* bo = (const float*)d_in[8];
  float* out = (float*)d_out;

  char* ws = (char*)d_ws;
  size_t off = 0;
  auto alloc = [&](size_t bytes) { char* p = ws + off; off += (bytes + 255) & ~255ULL; return p; };
  bf16_t* xb   = (bf16_t*)alloc((size_t)BS * DM * 2);
  bf16_t* Wcat = (bf16_t*)alloc((size_t)NQKV * DM * 2);
  bf16_t* Wob  = (bf16_t*)alloc((size_t)DM * DM * 2);
  float*  bcat = (float*)alloc((size_t)NQKV * 4);
  float2* rt   = (float2*)alloc((size_t)SEQ * 32 * 8);
  bf16_t* Qh   = (bf16_t*)alloc((size_t)BS * DM * 2);
  bf16_t* Kh   = (bf16_t*)alloc((size_t)BS * DM * 2);
  bf16_t* Vth  = (bf16_t*)alloc((size_t)BS * DM * 2);
  bf16_t* Oh   = (bf16_t*)alloc((size_t)BS * DM * 2);
  (void)ws_size; (void)in_sizes; (void)n_in; (void)out_size;

  k_cast_all<<<4099 + 256, 256, 0, stream>>>(x, Wq, Wk, Wv, Wo, bq, bk, bv,
                                             xb, Wcat, Wob, bcat, rt);

  dim3 gqkv(24, 32);
  k_gemm_qkv<<<gqkv, 256, 0, stream>>>(xb, Wcat, bcat, rt, Qh, Kh, Vth);
  k_attn<<<32 * 32, 256, 0, stream>>>(Qh, Kh, Vth, Oh);
  dim3 g2(DM / 128, BS / 128);
  k_gemm_out<<<g2, 512, 0, stream>>>(Oh, Wob, bo, out);
}

// Round 15
// 122.225 us; speedup vs baseline: 1.2651x; 1.1450x over previous
//
#include <hip/hip_runtime.h>
#include <hip/hip_bf16.h>
#include <stdint.h>

typedef __bf16 bf16_t;
typedef __bf16 bf16x4 __attribute__((ext_vector_type(4)));
typedef __bf16 bf16x8 __attribute__((ext_vector_type(8)));
typedef float  f32x4  __attribute__((ext_vector_type(4)));

#define DM    1024
#define NH    16
#define HD    64
#define SEQ   2048
#define BATCH 2
#define BS    (BATCH*SEQ)   // 4096
#define NQKV  (3*DM)        // 3072

#define GLOAD_LDS16(g, l) \
  __builtin_amdgcn_global_load_lds((const __attribute__((address_space(1))) void*)(g), \
                                   (__attribute__((address_space(3))) void*)(l), 16, 0, 0)

__device__ __forceinline__ f32x4 mfma16(bf16x8 a, bf16x8 b, f32x4 c) {
  return __builtin_amdgcn_mfma_f32_16x16x32_bf16(a, b, c, 0, 0, 0);
}

// ---------------- merged cast/copy + rope-table kernel ----------------
__global__ __launch_bounds__(256) void k_cast_all(
    const float* __restrict__ x,  const float* __restrict__ Wq,
    const float* __restrict__ Wk, const float* __restrict__ Wv,
    const float* __restrict__ Wo, const float* __restrict__ bq,
    const float* __restrict__ bk, const float* __restrict__ bv,
    bf16_t* __restrict__ xb, bf16_t* __restrict__ Wcat,
    bf16_t* __restrict__ Wob, float* __restrict__ bcat,
    float2* __restrict__ rt)
{
  const int bid = blockIdx.x, tid = threadIdx.x;
  if (bid >= 4099) {
    const int idx = (bid - 4099) * 256 + tid;   // SEQ*32 = 65536 entries
    const int s = idx >> 5, i = idx & 31;
    float inv = powf(10000.0f, -(float)(2 * i) / 64.0f);
    float ang = (float)s * inv;
    rt[idx] = make_float2(cosf(ang), sinf(ang));
    return;
  }
  if (bid >= 4096) {
    const int k = bid - 4096;
    const float* src = (k == 0) ? bq : (k == 1) ? bk : bv;
    *(float4*)&bcat[k * DM + tid * 4] = *(const float4*)&src[tid * 4];
    return;
  }
  const float* src; bf16_t* dst; int i;
  if (bid < 2048)      { src = x;  dst = xb;                i = bid * 2048 + tid * 8; }
  else if (bid < 2560) { src = Wq; dst = Wcat;              i = (bid - 2048) * 2048 + tid * 8; }
  else if (bid < 3072) { src = Wk; dst = Wcat + DM * DM;    i = (bid - 2560) * 2048 + tid * 8; }
  else if (bid < 3584) { src = Wv; dst = Wcat + 2 * DM * DM;i = (bid - 3072) * 2048 + tid * 8; }
  else                 { src = Wo; dst = Wob;               i = (bid - 3584) * 2048 + tid * 8; }
  float4 a = *(const float4*)(src + i);
  float4 b = *(const float4*)(src + i + 4);
  bf16x8 o;
  o[0] = (bf16_t)a.x; o[1] = (bf16_t)a.y; o[2] = (bf16_t)a.z; o[3] = (bf16_t)a.w;
  o[4] = (bf16_t)b.x; o[5] = (bf16_t)b.y; o[6] = (bf16_t)b.z; o[7] = (bf16_t)b.w;
  *(bf16x8*)(dst + i) = o;
}

// ---------------- Q/K projection GEMM (C^T) + bias + RoPE, LDS double-buffered ---
__global__ __launch_bounds__(256) void k_gemm_qk(
    const bf16_t* __restrict__ A, const bf16_t* __restrict__ B,
    const float* __restrict__ bias, const float2* __restrict__ rt,
    bf16_t* __restrict__ Qo, bf16_t* __restrict__ Ko)
{
  const int K = DM;
  __shared__ __align__(16) bf16_t As[2][128 * 32];
  __shared__ __align__(16) bf16_t Bs[2][128 * 32];
  const int tid  = threadIdx.x;
  const int lane = tid & 63;
  const int wave = tid >> 6;
  const int wr = wave >> 1, wc = wave & 1;
  const int m0 = blockIdx.y * 128, n0 = blockIdx.x * 128;
  const int c16 = lane & 15, g = lane >> 4;

  f32x4 acc[4][4];
  #pragma unroll
  for (int i = 0; i < 4; ++i)
    #pragma unroll
    for (int j = 0; j < 4; ++j)
      #pragma unroll
      for (int e = 0; e < 4; ++e) acc[i][j][e] = 0.0f;

  const int srow = wave * 32;
  const int lrow = lane >> 2;
  const int lk   = (lane & 3) * 8;
  const bf16_t* ga0 = A + (size_t)(m0 + srow +      lrow) * K + lk;
  const bf16_t* ga1 = A + (size_t)(m0 + srow + 16 + lrow) * K + lk;
  const bf16_t* gb0 = B + (size_t)(n0 + srow +      lrow) * K + lk;
  const bf16_t* gb1 = B + (size_t)(n0 + srow + 16 + lrow) * K + lk;
  bf16_t* la0A = &As[0][(srow) * 32];      bf16_t* la0B = &As[1][(srow) * 32];
  bf16_t* la1A = &As[0][(srow + 16) * 32]; bf16_t* la1B = &As[1][(srow + 16) * 32];
  bf16_t* lb0A = &Bs[0][(srow) * 32];      bf16_t* lb0B = &Bs[1][(srow) * 32];
  bf16_t* lb1A = &Bs[0][(srow + 16) * 32]; bf16_t* lb1B = &Bs[1][(srow + 16) * 32];

  const int po = (wr * 64 + c16) * 32 + g * 8;
  const int qo = (wc * 64 + c16) * 32 + g * 8;
  const bf16_t* paA = &As[0][po]; const bf16_t* paB = &As[1][po];
  const bf16_t* pbA = &Bs[0][qo]; const bf16_t* pbB = &Bs[1][qo];

  GLOAD_LDS16(ga0, la0A); GLOAD_LDS16(ga1, la1A);
  GLOAD_LDS16(gb0, lb0A); GLOAD_LDS16(gb1, lb1A);
  __syncthreads();

  for (int it = 0; it < K / 32; ++it) {
    const bool odd = it & 1;
    const int kt = it * 32;
    if (kt + 32 < K) {
      GLOAD_LDS16(ga0 + kt + 32, odd ? la0A : la0B);
      GLOAD_LDS16(ga1 + kt + 32, odd ? la1A : la1B);
      GLOAD_LDS16(gb0 + kt + 32, odd ? lb0A : lb0B);
      GLOAD_LDS16(gb1 + kt + 32, odd ? lb1A : lb1B);
    }
    const bf16_t* pa = odd ? paB : paA;
    const bf16_t* pb = odd ? pbB : pbA;
    bf16x8 af[4], bfr[4];
    #pragma unroll
    for (int t = 0; t < 4; ++t) af[t]  = *(const bf16x8*)(pa + t * 16 * 32);
    #pragma unroll
    for (int t = 0; t < 4; ++t) bfr[t] = *(const bf16x8*)(pb + t * 16 * 32);
    #pragma unroll
    for (int i = 0; i < 4; ++i)
      #pragma unroll
      for (int j = 0; j < 4; ++j)
        acc[i][j] = mfma16(bfr[j], af[i], acc[i][j]);   // SWAPPED -> C^T layout
    __syncthreads();
  }

  const int region = n0 >> 10;                 // 0=Q, 1=K
  bf16_t* dst = region ? Ko : Qo;
  const float qs = region ? 1.0f : (0.125f * 1.44269504088896f);
  #pragma unroll
  for (int j = 0; j < 4; ++j) {
    const int nb = n0 + wc * 64 + j * 16 + (g << 2);   // n of e=0
    const float4 bv = *(const float4*)&bias[nb];
    const int h  = (nb >> 6) & 15;
    const int d0 = nb & 63;
    #pragma unroll
    for (int i = 0; i < 4; ++i) {
      const int m = m0 + wr * 64 + i * 16 + c16;
      const int s = m & 2047;
      const int bh = ((m >> 11) << 4) + h;
      const float4 cs = *(const float4*)&rt[(size_t)s * 32 + (d0 >> 1)];
      const float v0 = acc[i][j][0] + bv.x;
      const float v1 = acc[i][j][1] + bv.y;
      const float v2 = acc[i][j][2] + bv.z;
      const float v3 = acc[i][j][3] + bv.w;
      bf16x4 ov;
      ov[0] = (bf16_t)((v0 * cs.x - v1 * cs.y) * qs);
      ov[1] = (bf16_t)((v0 * cs.y + v1 * cs.x) * qs);
      ov[2] = (bf16_t)((v2 * cs.z - v3 * cs.w) * qs);
      ov[3] = (bf16_t)((v2 * cs.w + v3 * cs.z) * qs);
      *(bf16x4*)&dst[((size_t)bh * SEQ + s) * HD + d0] = ov;
    }
  }
}

// ---------------- V projection GEMM + bias + PERMUTED V^T, LDS double-buffered ---
__global__ __launch_bounds__(256) void k_gemm_v(
    const bf16_t* __restrict__ A, const bf16_t* __restrict__ B,
    const float* __restrict__ bias, bf16_t* __restrict__ Vt)
{
  const int K = DM;
  __shared__ __align__(16) bf16_t As[2][128 * 32];
  __shared__ __align__(16) bf16_t Bs[2][128 * 32];
  const int tid  = threadIdx.x;
  const int lane = tid & 63;
  const int wave = tid >> 6;
  const int wr = wave >> 1, wc = wave & 1;
  const int m0 = blockIdx.y * 128, n0 = blockIdx.x * 128;
  const int c16 = lane & 15, g = lane >> 4;

  f32x4 acc[4][4];
  #pragma unroll
  for (int i = 0; i < 4; ++i)
    #pragma unroll
    for (int j = 0; j < 4; ++j)
      #pragma unroll
      for (int e = 0; e < 4; ++e) acc[i][j][e] = 0.0f;

  const int srow = wave * 32;
  const int lrow = lane >> 2;
  const int lk   = (lane & 3) * 8;
  const bf16_t* ga0 = A + (size_t)(m0 + srow +      lrow) * K + lk;
  const bf16_t* ga1 = A + (size_t)(m0 + srow + 16 + lrow) * K + lk;
  const bf16_t* gb0 = B + (size_t)(n0 + srow +      lrow) * K + lk;
  const bf16_t* gb1 = B + (size_t)(n0 + srow + 16 + lrow) * K + lk;
  bf16_t* la0A = &As[0][(srow) * 32];      bf16_t* la0B = &As[1][(srow) * 32];
  bf16_t* la1A = &As[0][(srow + 16) * 32]; bf16_t* la1B = &As[1][(srow + 16) * 32];
  bf16_t* lb0A = &Bs[0][(srow) * 32];      bf16_t* lb0B = &Bs[1][(srow) * 32];
  bf16_t* lb1A = &Bs[0][(srow + 16) * 32]; bf16_t* lb1B = &Bs[1][(srow + 16) * 32];

  const int po = (wr * 64 + c16) * 32 + g * 8;
  const int qo = (wc * 64 + c16) * 32 + g * 8;
  const bf16_t* paA = &As[0][po]; const bf16_t* paB = &As[1][po];
  const bf16_t* pbA = &Bs[0][qo]; const bf16_t* pbB = &Bs[1][qo];

  GLOAD_LDS16(ga0, la0A); GLOAD_LDS16(ga1, la1A);
  GLOAD_LDS16(gb0, lb0A); GLOAD_LDS16(gb1, lb1A);
  __syncthreads();

  for (int it = 0; it < K / 32; ++it) {
    const bool odd = it & 1;
    const int kt = it * 32;
    if (kt + 32 < K) {
      GLOAD_LDS16(ga0 + kt + 32, odd ? la0A : la0B);
      GLOAD_LDS16(ga1 + kt + 32, odd ? la1A : la1B);
      GLOAD_LDS16(gb0 + kt + 32, odd ? lb0A : lb0B);
      GLOAD_LDS16(gb1 + kt + 32, odd ? lb1A : lb1B);
    }
    const bf16_t* pa = odd ? paB : paA;
    const bf16_t* pb = odd ? pbB : pbA;
    bf16x8 af[4], bfr[4];
    #pragma unroll
    for (int t = 0; t < 4; ++t) af[t]  = *(const bf16x8*)(pa + t * 16 * 32);
    #pragma unroll
    for (int t = 0; t < 4; ++t) bfr[t] = *(const bf16x8*)(pb + t * 16 * 32);
    #pragma unroll
    for (int i = 0; i < 4; ++i)
      #pragma unroll
      for (int j = 0; j < 4; ++j)
        acc[i][j] = mfma16(af[i], bfr[j], acc[i][j]);
    __syncthreads();
  }

  const int rbase = m0 + wr * 64 + (g << 2);
  const int cbase = n0 + wc * 64 + c16;
  #pragma unroll
  for (int j = 0; j < 4; ++j) {
    const int c = cbase + j * 16;
    const float bv = bias[c];
    const int h = (c >> 6) & 15;
    const int d = c & 63;
    #pragma unroll
    for (int i = 0; i < 4; ++i) {
      bf16x4 ov;
      #pragma unroll
      for (int e = 0; e < 4; ++e) ov[e] = (bf16_t)(acc[i][j][e] + bv);
      const int r0 = rbase + i * 16;
      const int bh = ((r0 >> 11) << 4) + h;
      const int s0 = r0 & 2047;
      const int u  = (s0 >> 4) & 3;
      const int p0 = (s0 & ~63) + ((u >> 1) << 5) + (g << 3) + ((u & 1) << 2);
      *(bf16x4*)&Vt[((size_t)bh * HD + d) * SEQ + p0] = ov;
    }
  }
}

// ---------------- output projection GEMM: 8 waves, LDS double-buffered ----------
__global__ __launch_bounds__(512) void k_gemm_out(
    const bf16_t* __restrict__ A, const bf16_t* __restrict__ B,
    const float* __restrict__ bias, float* __restrict__ C)
{
  const int K = DM, N = DM;
  __shared__ __align__(16) bf16_t As[2][128 * 32];
  __shared__ __align__(16) bf16_t Bs[2][128 * 32];
  const int tid  = threadIdx.x;
  const int lane = tid & 63;
  const int w    = tid >> 6;
  const int wr = w >> 2, wc = w & 3;
  const int m0 = blockIdx.y * 128, n0 = blockIdx.x * 128;
  const int c16 = lane & 15, g = lane >> 4;

  f32x4 acc[4][2];
  #pragma unroll
  for (int i = 0; i < 4; ++i)
    #pragma unroll
    for (int j = 0; j < 2; ++j)
      #pragma unroll
      for (int e = 0; e < 4; ++e) acc[i][j][e] = 0.0f;

  const int lrow = lane >> 2;
  const int lk   = (lane & 3) * 8;
  const bf16_t* ga = A + (size_t)(m0 + w * 16 + lrow) * K + lk;
  const bf16_t* gb = B + (size_t)(n0 + w * 16 + lrow) * K + lk;
  bf16_t* laA = &As[0][(w * 16) * 32]; bf16_t* laB = &As[1][(w * 16) * 32];
  bf16_t* lbA = &Bs[0][(w * 16) * 32]; bf16_t* lbB = &Bs[1][(w * 16) * 32];

  const int po = (wr * 64 + c16) * 32 + g * 8;
  const int qo = (wc * 32 + c16) * 32 + g * 8;
  const bf16_t* paA = &As[0][po]; const bf16_t* paB = &As[1][po];
  const bf16_t* pbA = &Bs[0][qo]; const bf16_t* pbB = &Bs[1][qo];

  GLOAD_LDS16(ga, laA); GLOAD_LDS16(gb, lbA);
  __syncthreads();

  for (int it = 0; it < K / 32; ++it) {
    const bool odd = it & 1;
    const int kt = it * 32;
    if (kt + 32 < K) {
      GLOAD_LDS16(ga + kt + 32, odd ? laA : laB);
      GLOAD_LDS16(gb + kt + 32, odd ? lbA : lbB);
    }
    const bf16_t* pa = odd ? paB : paA;
    const bf16_t* pb = odd ? pbB : pbA;
    bf16x8 af[4], bfr[2];
    #pragma unroll
    for (int t = 0; t < 4; ++t) af[t]  = *(const bf16x8*)(pa + t * 16 * 32);
    #pragma unroll
    for (int t = 0; t < 2; ++t) bfr[t] = *(const bf16x8*)(pb + t * 16 * 32);
    #pragma unroll
    for (int i = 0; i < 4; ++i)
      #pragma unroll
      for (int j = 0; j < 2; ++j)
        acc[i][j] = mfma16(af[i], bfr[j], acc[i][j]);
    __syncthreads();
  }

  const int rbase = m0 + wr * 64 + (g << 2);
  const int cbase = n0 + wc * 32 + c16;
  #pragma unroll
  for (int j = 0; j < 2; ++j) {
    const int c = cbase + j * 16;
    const float bv = bias[c];
    #pragma unroll
    for (int i = 0; i < 4; ++i) {
      #pragma unroll
      for (int e = 0; e < 4; ++e) {
        const int r = rbase + i * 16 + e;
        C[(size_t)r * N + c] = acc[i][j][e] + bv;
      }
    }
  }
}

// ---------------- flash attention (r11 version, 44 us measured) ----------------
__global__ __launch_bounds__(256, 4) void k_attn(
    const bf16_t* __restrict__ Q, const bf16_t* __restrict__ K,
    const bf16_t* __restrict__ Vt, bf16_t* __restrict__ O)
{
  __shared__ __align__(16) bf16_t kbuf[2][64 * 64];
  __shared__ __align__(16) bf16_t vbuf[2][64 * 64];
  const int tid = threadIdx.x, lane = tid & 63, w = tid >> 6;
  const int rr = blockIdx.x >> 8;          // 0..3
  const int kk = (blockIdx.x >> 5) & 7;    // 0..7
  const int bh = blockIdx.x & 31;
  const int qt = (rr == 0) ? kk : (rr == 1) ? 15 - kk : (rr == 2) ? 16 + kk : 31 - kk;
  const int b  = bh >> 4, h = bh & 15;
  const int q0 = qt * 64 + w * 16;
  const int c16 = lane & 15;
  const int g   = lane >> 4;
  const int q   = q0 + c16;

  const bf16_t* Qb = Q  + (size_t)bh * SEQ * HD;
  const bf16_t* Kb = K  + (size_t)bh * SEQ * HD;
  const bf16_t* Vb = Vt + (size_t)bh * HD * SEQ;

  bf16x8 qf0 = *(const bf16x8*)&Qb[(size_t)q * HD + g * 8];
  bf16x8 qf1 = *(const bf16x8*)&Qb[(size_t)q * HD + 32 + g * 8];

  f32x4 oacc[4];
  #pragma unroll
  for (int dblk = 0; dblk < 4; ++dblk)
    #pragma unroll
    for (int e = 0; e < 4; ++e) oacc[dblk][e] = 0.0f;
  float m_ = -1e30f, l_ = 0.0f;

  const int ntile = qt + 1;

  const int soff0 = w * 1024 + lane * 16;
  const int soff1 = soff0 + 4096;
  const int srow0 = soff0 >> 7, srow1 = soff1 >> 7;
  const int scb0  = (soff0 & 127) ^ ((srow0 & 7) << 4);
  const int scb1  = (soff1 & 127) ^ ((srow1 & 7) << 4);
  const bf16_t* gk0 = &Kb[(size_t)srow0 * HD + (scb0 >> 1)];
  const bf16_t* gk1 = &Kb[(size_t)srow1 * HD + (scb1 >> 1)];
  const bf16_t* gv0 = &Vb[(size_t)srow0 * SEQ + (scb0 >> 1)];
  const bf16_t* gv1 = &Vb[(size_t)srow1 * SEQ + (scb1 >> 1)];
  bf16_t* lk0A = &kbuf[0][(w * 1024) >> 1];
  bf16_t* lk1A = &kbuf[0][(w * 1024 + 4096) >> 1];
  bf16_t* lk0B = &kbuf[1][(w * 1024) >> 1];
  bf16_t* lk1B = &kbuf[1][(w * 1024 + 4096) >> 1];
  bf16_t* lv0A = &vbuf[0][(w * 1024) >> 1];
  bf16_t* lv1A = &vbuf[0][(w * 1024 + 4096) >> 1];
  bf16_t* lv0B = &vbuf[1][(w * 1024) >> 1];
  bf16_t* lv1B = &vbuf[1][(w * 1024 + 4096) >> 1];

  const int sw = (c16 & 7) << 4;
  const int e0 = ((16 * g) ^ sw) >> 1;
  const int dhi = (((64 + 16 * g) ^ sw) >> 1) - e0;
  const bf16_t* kp0 = &kbuf[0][c16 * 64 + e0];
  const bf16_t* kp1 = &kbuf[1][c16 * 64 + e0];
  const bf16_t* vp0 = &vbuf[0][c16 * 64 + e0];
  const bf16_t* vp1 = &vbuf[1][c16 * 64 + e0];

  GLOAD_LDS16(gk0, lk0A); GLOAD_LDS16(gk1, lk1A);
  GLOAD_LDS16(gv0, lv0A); GLOAD_LDS16(gv1, lv1A);
  gk0 += 4096; gk1 += 4096; gv0 += 64; gv1 += 64;
  __syncthreads();

  for (int t = 0; t < ntile; ++t) {
    const bool odd = t & 1;
    if (t + 1 < ntile) {
      GLOAD_LDS16(gk0, odd ? lk0A : lk0B); GLOAD_LDS16(gk1, odd ? lk1A : lk1B);
      GLOAD_LDS16(gv0, odd ? lv0A : lv0B); GLOAD_LDS16(gv1, odd ? lv1A : lv1B);
      gk0 += 4096; gk1 += 4096; gv0 += 64; gv1 += 64;
    }

    const bf16_t* kp = odd ? kp1 : kp0;
    const bf16_t* vp = odd ? vp1 : vp0;

    f32x4 st[4];
    __builtin_amdgcn_s_setprio(1);
    #pragma unroll
    for (int u = 0; u < 4; ++u) {
      bf16x8 k0 = *(const bf16x8*)(kp + u * 1024);
      bf16x8 k1 = *(const bf16x8*)(kp + u * 1024 + dhi);
      f32x4 z; z[0] = z[1] = z[2] = z[3] = 0.0f;
      z = mfma16(k0, qf0, z);
      z = mfma16(k1, qf1, z);
      st[u] = z;
    }
    __builtin_amdgcn_s_setprio(0);

    bf16x8 vlo[4], vhi[4];
    #pragma unroll
    for (int dblk = 0; dblk < 4; ++dblk) {
      vlo[dblk] = *(const bf16x8*)(vp + dblk * 1024);
      vhi[dblk] = *(const bf16x8*)(vp + dblk * 1024 + dhi);
    }

    float pv[16];
    if (t == qt) {
      const int kv0 = t * 64;
      #pragma unroll
      for (int u = 0; u < 4; ++u)
        #pragma unroll
        for (int r = 0; r < 4; ++r) {
          const int kv = kv0 + 16 * u + 4 * g + r;
          pv[u * 4 + r] = (kv <= q) ? st[u][r] : -1e30f;
        }
    } else {
      #pragma unroll
      for (int u = 0; u < 4; ++u)
        #pragma unroll
        for (int r = 0; r < 4; ++r)
          pv[u * 4 + r] = st[u][r];
    }

    float ma = fmaxf(fmaxf(pv[0], pv[1]), fmaxf(pv[2], pv[3]));
    float mb = fmaxf(fmaxf(pv[4], pv[5]), fmaxf(pv[6], pv[7]));
    float mc = fmaxf(fmaxf(pv[8], pv[9]), fmaxf(pv[10], pv[11]));
    float md = fmaxf(fmaxf(pv[12], pv[13]), fmaxf(pv[14], pv[15]));
    const float lmx = fmaxf(fmaxf(ma, mb), fmaxf(mc, md));

    if (__any(lmx - m_ > 12.0f)) {
      float mx = fmaxf(lmx, __shfl_xor(lmx, 16));
      mx = fmaxf(mx, __shfl_xor(mx, 32));
      const float mn = fmaxf(m_, mx);
      const float alpha = exp2f(m_ - mn);
      l_ *= alpha;
      #pragma unroll
      for (int dblk = 0; dblk < 4; ++dblk)
        #pragma unroll
        for (int e = 0; e < 4; ++e) oacc[dblk][e] *= alpha;
      m_ = mn;
    }

    #pragma unroll
    for (int i = 0; i < 16; ++i) pv[i] = exp2f(pv[i] - m_);
    float s0 = (pv[0] + pv[1]) + (pv[2] + pv[3]);
    float s1 = (pv[4] + pv[5]) + (pv[6] + pv[7]);
    float s2 = (pv[8] + pv[9]) + (pv[10] + pv[11]);
    float s3 = (pv[12] + pv[13]) + (pv[14] + pv[15]);
    l_ += (s0 + s1) + (s2 + s3);

    bf16x8 pf0, pf1;
    #pragma unroll
    for (int j = 0; j < 8; ++j) {
      pf0[j] = (bf16_t)pv[j];
      pf1[j] = (bf16_t)pv[8 + j];
    }

    __builtin_amdgcn_s_setprio(1);
    #pragma unroll
    for (int dblk = 0; dblk < 4; ++dblk) {
      oacc[dblk] = mfma16(vlo[dblk], pf0, oacc[dblk]);
      oacc[dblk] = mfma16(vhi[dblk], pf1, oacc[dblk]);
    }
    __builtin_amdgcn_s_setprio(0);

    __syncthreads();
  }

  l_ += __shfl_xor(l_, 16);
  l_ += __shfl_xor(l_, 32);
  const float inv = 1.0f / l_;
  bf16_t* orow = O + ((size_t)(b * SEQ + q)) * DM + h * HD;
  #pragma unroll
  for (int dblk = 0; dblk < 4; ++dblk) {
    bf16x4 ov;
    #pragma unroll
    for (int r = 0; r < 4; ++r) ov[r] = (bf16_t)(oacc[dblk][r] * inv);
    *(bf16x4*)&orow[dblk * 16 + 4 * g] = ov;
  }
}

// ---------------- launch ----------------
extern "C" void kernel_launch(void* const* d_in, const int* in_sizes, int n_in,
                              void* d_out, int out_size, void* d_ws, size_t ws_size,
                              hipStream_t stream)
{
  const float* x  = (const float*)d_in[0];
  const float* Wq = (const float*)d_in[1];
  const float* bq = (const float*)d_in[2];
  const float* Wk = (const float*)d_in[3];
  const float* bk = (const float*)d_in[4];
  const float* Wv = (const float*)d_in[5];
  const float* bv = (const float*)d_in[6];
  const float* Wo = (const float*)d_in[7];
  const float* bo = (const float*)d_in[8];
  float* out = (float*)d_out;

  char* ws = (char*)d_ws;
  size_t off = 0;
  auto alloc = [&](size_t bytes) { char* p = ws + off; off += (bytes + 255) & ~255ULL; return p; };
  bf16_t* xb   = (bf16_t*)alloc((size_t)BS * DM * 2);
  bf16_t* Wcat = (bf16_t*)alloc((size_t)NQKV * DM * 2);
  bf16_t* Wob  = (bf16_t*)alloc((size_t)DM * DM * 2);
  float*  bcat = (float*)alloc((size_t)NQKV * 4);
  float2* rt   = (float2*)alloc((size_t)SEQ * 32 * 8);
  bf16_t* Qh   = (bf16_t*)alloc((size_t)BS * DM * 2);
  bf16_t* Kh   = (bf16_t*)alloc((size_t)BS * DM * 2);
  bf16_t* Vth  = (bf16_t*)alloc((size_t)BS * DM * 2);
  bf16_t* Oh   = (bf16_t*)alloc((size_t)BS * DM * 2);
  (void)ws_size; (void)in_sizes; (void)n_in; (void)out_size;

  k_cast_all<<<4099 + 256, 256, 0, stream>>>(x, Wq, Wk, Wv, Wo, bq, bk, bv,
                                             xb, Wcat, Wob, bcat, rt);

  dim3 gqk(16, 32);
  k_gemm_qk<<<gqk, 256, 0, stream>>>(xb, Wcat, bcat, rt, Qh, Kh);
  dim3 gv(8, 32);
  k_gemm_v<<<gv, 256, 0, stream>>>(xb, Wcat + 2 * DM * DM, bcat + 2 * DM, Vth);
  k_attn<<<32 * 32, 256, 0, stream>>>(Qh, Kh, Vth, Oh);
  dim3 g2(DM / 128, BS / 128);
  k_gemm_out<<<g2, 512, 0, stream>>>(Oh, Wob, bo, out);
}

// Round 16
// 121.464 us; speedup vs baseline: 1.2731x; 1.0063x over previous
//
#include <hip/hip_runtime.h>
#include <hip/hip_bf16.h>
#include <stdint.h>

typedef __bf16 bf16_t;
typedef __bf16 bf16x4 __attribute__((ext_vector_type(4)));
typedef __bf16 bf16x8 __attribute__((ext_vector_type(8)));
typedef float  f32x4  __attribute__((ext_vector_type(4)));

#define DM    1024
#define NH    16
#define HD    64
#define SEQ   2048
#define BATCH 2
#define BS    (BATCH*SEQ)   // 4096
#define NQKV  (3*DM)        // 3072

#define GLOAD_LDS16(g, l) \
  __builtin_amdgcn_global_load_lds((const __attribute__((address_space(1))) void*)(g), \
                                   (__attribute__((address_space(3))) void*)(l), 16, 0, 0)

__device__ __forceinline__ f32x4 mfma16(bf16x8 a, bf16x8 b, f32x4 c) {
  return __builtin_amdgcn_mfma_f32_16x16x32_bf16(a, b, c, 0, 0, 0);
}

// ---------------- merged cast/copy + rope-table kernel ----------------
__global__ __launch_bounds__(256) void k_cast_all(
    const float* __restrict__ x,  const float* __restrict__ Wq,
    const float* __restrict__ Wk, const float* __restrict__ Wv,
    const float* __restrict__ Wo, const float* __restrict__ bq,
    const float* __restrict__ bk, const float* __restrict__ bv,
    bf16_t* __restrict__ xb, bf16_t* __restrict__ Wcat,
    bf16_t* __restrict__ Wob, float* __restrict__ bcat,
    float2* __restrict__ rt)
{
  const int bid = blockIdx.x, tid = threadIdx.x;
  if (bid >= 4099) {
    const int idx = (bid - 4099) * 256 + tid;   // SEQ*32 = 65536 entries
    const int s = idx >> 5, i = idx & 31;
    float inv = powf(10000.0f, -(float)(2 * i) / 64.0f);
    float ang = (float)s * inv;
    rt[idx] = make_float2(cosf(ang), sinf(ang));
    return;
  }
  if (bid >= 4096) {
    const int k = bid - 4096;
    const float* src = (k == 0) ? bq : (k == 1) ? bk : bv;
    *(float4*)&bcat[k * DM + tid * 4] = *(const float4*)&src[tid * 4];
    return;
  }
  const float* src; bf16_t* dst; int i;
  if (bid < 2048)      { src = x;  dst = xb;                i = bid * 2048 + tid * 8; }
  else if (bid < 2560) { src = Wq; dst = Wcat;              i = (bid - 2048) * 2048 + tid * 8; }
  else if (bid < 3072) { src = Wk; dst = Wcat + DM * DM;    i = (bid - 2560) * 2048 + tid * 8; }
  else if (bid < 3584) { src = Wv; dst = Wcat + 2 * DM * DM;i = (bid - 3072) * 2048 + tid * 8; }
  else                 { src = Wo; dst = Wob;               i = (bid - 3584) * 2048 + tid * 8; }
  float4 a = *(const float4*)(src + i);
  float4 b = *(const float4*)(src + i + 4);
  bf16x8 o;
  o[0] = (bf16_t)a.x; o[1] = (bf16_t)a.y; o[2] = (bf16_t)a.z; o[3] = (bf16_t)a.w;
  o[4] = (bf16_t)b.x; o[5] = (bf16_t)b.y; o[6] = (bf16_t)b.z; o[7] = (bf16_t)b.w;
  *(bf16x8*)(dst + i) = o;
}

// ---------------- Q/K projection GEMM (C^T) + bias + RoPE, LDS double-buffered ---
__global__ __launch_bounds__(256) void k_gemm_qk(
    const bf16_t* __restrict__ A, const bf16_t* __restrict__ B,
    const float* __restrict__ bias, const float2* __restrict__ rt,
    bf16_t* __restrict__ Qo, bf16_t* __restrict__ Ko)
{
  const int K = DM;
  __shared__ __align__(16) bf16_t As[2][128 * 32];
  __shared__ __align__(16) bf16_t Bs[2][128 * 32];
  const int tid  = threadIdx.x;
  const int lane = tid & 63;
  const int wave = tid >> 6;
  const int wr = wave >> 1, wc = wave & 1;
  const int m0 = blockIdx.y * 128, n0 = blockIdx.x * 128;
  const int c16 = lane & 15, g = lane >> 4;

  f32x4 acc[4][4];
  #pragma unroll
  for (int i = 0; i < 4; ++i)
    #pragma unroll
    for (int j = 0; j < 4; ++j)
      #pragma unroll
      for (int e = 0; e < 4; ++e) acc[i][j][e] = 0.0f;

  const int srow = wave * 32;
  const int lrow = lane >> 2;
  const int lk   = (lane & 3) * 8;
  const bf16_t* ga0 = A + (size_t)(m0 + srow +      lrow) * K + lk;
  const bf16_t* ga1 = A + (size_t)(m0 + srow + 16 + lrow) * K + lk;
  const bf16_t* gb0 = B + (size_t)(n0 + srow +      lrow) * K + lk;
  const bf16_t* gb1 = B + (size_t)(n0 + srow + 16 + lrow) * K + lk;
  bf16_t* la0A = &As[0][(srow) * 32];      bf16_t* la0B = &As[1][(srow) * 32];
  bf16_t* la1A = &As[0][(srow + 16) * 32]; bf16_t* la1B = &As[1][(srow + 16) * 32];
  bf16_t* lb0A = &Bs[0][(srow) * 32];      bf16_t* lb0B = &Bs[1][(srow) * 32];
  bf16_t* lb1A = &Bs[0][(srow + 16) * 32]; bf16_t* lb1B = &Bs[1][(srow + 16) * 32];

  const int po = (wr * 64 + c16) * 32 + g * 8;
  const int qo = (wc * 64 + c16) * 32 + g * 8;
  const bf16_t* paA = &As[0][po]; const bf16_t* paB = &As[1][po];
  const bf16_t* pbA = &Bs[0][qo]; const bf16_t* pbB = &Bs[1][qo];

  GLOAD_LDS16(ga0, la0A); GLOAD_LDS16(ga1, la1A);
  GLOAD_LDS16(gb0, lb0A); GLOAD_LDS16(gb1, lb1A);
  __syncthreads();

  for (int it = 0; it < K / 32; ++it) {
    const bool odd = it & 1;
    const int kt = it * 32;
    if (kt + 32 < K) {
      GLOAD_LDS16(ga0 + kt + 32, odd ? la0A : la0B);
      GLOAD_LDS16(ga1 + kt + 32, odd ? la1A : la1B);
      GLOAD_LDS16(gb0 + kt + 32, odd ? lb0A : lb0B);
      GLOAD_LDS16(gb1 + kt + 32, odd ? lb1A : lb1B);
    }
    const bf16_t* pa = odd ? paB : paA;
    const bf16_t* pb = odd ? pbB : pbA;
    bf16x8 af[4], bfr[4];
    #pragma unroll
    for (int t = 0; t < 4; ++t) af[t]  = *(const bf16x8*)(pa + t * 16 * 32);
    #pragma unroll
    for (int t = 0; t < 4; ++t) bfr[t] = *(const bf16x8*)(pb + t * 16 * 32);
    #pragma unroll
    for (int i = 0; i < 4; ++i)
      #pragma unroll
      for (int j = 0; j < 4; ++j)
        acc[i][j] = mfma16(bfr[j], af[i], acc[i][j]);   // SWAPPED -> C^T layout
    __syncthreads();
  }

  const int region = n0 >> 10;                 // 0=Q, 1=K
  bf16_t* dst = region ? Ko : Qo;
  const float qs = region ? 1.0f : (0.125f * 1.44269504088896f);
  #pragma unroll
  for (int j = 0; j < 4; ++j) {
    const int nb = n0 + wc * 64 + j * 16 + (g << 2);   // n of e=0
    const float4 bv = *(const float4*)&bias[nb];
    const int h  = (nb >> 6) & 15;
    const int d0 = nb & 63;
    #pragma unroll
    for (int i = 0; i < 4; ++i) {
      const int m = m0 + wr * 64 + i * 16 + c16;
      const int s = m & 2047;
      const int bh = ((m >> 11) << 4) + h;
      const float4 cs = *(const float4*)&rt[(size_t)s * 32 + (d0 >> 1)];
      const float v0 = acc[i][j][0] + bv.x;
      const float v1 = acc[i][j][1] + bv.y;
      const float v2 = acc[i][j][2] + bv.z;
      const float v3 = acc[i][j][3] + bv.w;
      bf16x4 ov;
      ov[0] = (bf16_t)((v0 * cs.x - v1 * cs.y) * qs);
      ov[1] = (bf16_t)((v0 * cs.y + v1 * cs.x) * qs);
      ov[2] = (bf16_t)((v2 * cs.z - v3 * cs.w) * qs);
      ov[3] = (bf16_t)((v2 * cs.w + v3 * cs.z) * qs);
      *(bf16x4*)&dst[((size_t)bh * SEQ + s) * HD + d0] = ov;
    }
  }
}

// ---------------- V projection GEMM + bias + PERMUTED V^T, LDS double-buffered ---
__global__ __launch_bounds__(256) void k_gemm_v(
    const bf16_t* __restrict__ A, const bf16_t* __restrict__ B,
    const float* __restrict__ bias, bf16_t* __restrict__ Vt)
{
  const int K = DM;
  __shared__ __align__(16) bf16_t As[2][128 * 32];
  __shared__ __align__(16) bf16_t Bs[2][128 * 32];
  const int tid  = threadIdx.x;
  const int lane = tid & 63;
  const int wave = tid >> 6;
  const int wr = wave >> 1, wc = wave & 1;
  const int m0 = blockIdx.y * 128, n0 = blockIdx.x * 128;
  const int c16 = lane & 15, g = lane >> 4;

  f32x4 acc[4][4];
  #pragma unroll
  for (int i = 0; i < 4; ++i)
    #pragma unroll
    for (int j = 0; j < 4; ++j)
      #pragma unroll
      for (int e = 0; e < 4; ++e) acc[i][j][e] = 0.0f;

  const int srow = wave * 32;
  const int lrow = lane >> 2;
  const int lk   = (lane & 3) * 8;
  const bf16_t* ga0 = A + (size_t)(m0 + srow +      lrow) * K + lk;
  const bf16_t* ga1 = A + (size_t)(m0 + srow + 16 + lrow) * K + lk;
  const bf16_t* gb0 = B + (size_t)(n0 + srow +      lrow) * K + lk;
  const bf16_t* gb1 = B + (size_t)(n0 + srow + 16 + lrow) * K + lk;
  bf16_t* la0A = &As[0][(srow) * 32];      bf16_t* la0B = &As[1][(srow) * 32];
  bf16_t* la1A = &As[0][(srow + 16) * 32]; bf16_t* la1B = &As[1][(srow + 16) * 32];
  bf16_t* lb0A = &Bs[0][(srow) * 32];      bf16_t* lb0B = &Bs[1][(srow) * 32];
  bf16_t* lb1A = &Bs[0][(srow + 16) * 32]; bf16_t* lb1B = &Bs[1][(srow + 16) * 32];

  const int po = (wr * 64 + c16) * 32 + g * 8;
  const int qo = (wc * 64 + c16) * 32 + g * 8;
  const bf16_t* paA = &As[0][po]; const bf16_t* paB = &As[1][po];
  const bf16_t* pbA = &Bs[0][qo]; const bf16_t* pbB = &Bs[1][qo];

  GLOAD_LDS16(ga0, la0A); GLOAD_LDS16(ga1, la1A);
  GLOAD_LDS16(gb0, lb0A); GLOAD_LDS16(gb1, lb1A);
  __syncthreads();

  for (int it = 0; it < K / 32; ++it) {
    const bool odd = it & 1;
    const int kt = it * 32;
    if (kt + 32 < K) {
      GLOAD_LDS16(ga0 + kt + 32, odd ? la0A : la0B);
      GLOAD_LDS16(ga1 + kt + 32, odd ? la1A : la1B);
      GLOAD_LDS16(gb0 + kt + 32, odd ? lb0A : lb0B);
      GLOAD_LDS16(gb1 + kt + 32, odd ? lb1A : lb1B);
    }
    const bf16_t* pa = odd ? paB : paA;
    const bf16_t* pb = odd ? pbB : pbA;
    bf16x8 af[4], bfr[4];
    #pragma unroll
    for (int t = 0; t < 4; ++t) af[t]  = *(const bf16x8*)(pa + t * 16 * 32);
    #pragma unroll
    for (int t = 0; t < 4; ++t) bfr[t] = *(const bf16x8*)(pb + t * 16 * 32);
    #pragma unroll
    for (int i = 0; i < 4; ++i)
      #pragma unroll
      for (int j = 0; j < 4; ++j)
        acc[i][j] = mfma16(af[i], bfr[j], acc[i][j]);
    __syncthreads();
  }

  const int rbase = m0 + wr * 64 + (g << 2);
  const int cbase = n0 + wc * 64 + c16;
  #pragma unroll
  for (int j = 0; j < 4; ++j) {
    const int c = cbase + j * 16;
    const float bv = bias[c];
    const int h = (c >> 6) & 15;
    const int d = c & 63;
    #pragma unroll
    for (int i = 0; i < 4; ++i) {
      bf16x4 ov;
      #pragma unroll
      for (int e = 0; e < 4; ++e) ov[e] = (bf16_t)(acc[i][j][e] + bv);
      const int r0 = rbase + i * 16;
      const int bh = ((r0 >> 11) << 4) + h;
      const int s0 = r0 & 2047;
      const int u  = (s0 >> 4) & 3;
      const int p0 = (s0 & ~63) + ((u >> 1) << 5) + (g << 3) + ((u & 1) << 2);
      *(bf16x4*)&Vt[((size_t)bh * HD + d) * SEQ + p0] = ov;
    }
  }
}

// ---------------- output projection GEMM: 8 waves, LDS double-buffered ----------
__global__ __launch_bounds__(512) void k_gemm_out(
    const bf16_t* __restrict__ A, const bf16_t* __restrict__ B,
    const float* __restrict__ bias, float* __restrict__ C)
{
  const int K = DM, N = DM;
  __shared__ __align__(16) bf16_t As[2][128 * 32];
  __shared__ __align__(16) bf16_t Bs[2][128 * 32];
  const int tid  = threadIdx.x;
  const int lane = tid & 63;
  const int w    = tid >> 6;
  const int wr = w >> 2, wc = w & 3;
  const int m0 = blockIdx.y * 128, n0 = blockIdx.x * 128;
  const int c16 = lane & 15, g = lane >> 4;

  f32x4 acc[4][2];
  #pragma unroll
  for (int i = 0; i < 4; ++i)
    #pragma unroll
    for (int j = 0; j < 2; ++j)
      #pragma unroll
      for (int e = 0; e < 4; ++e) acc[i][j][e] = 0.0f;

  const int lrow = lane >> 2;
  const int lk   = (lane & 3) * 8;
  const bf16_t* ga = A + (size_t)(m0 + w * 16 + lrow) * K + lk;
  const bf16_t* gb = B + (size_t)(n0 + w * 16 + lrow) * K + lk;
  bf16_t* laA = &As[0][(w * 16) * 32]; bf16_t* laB = &As[1][(w * 16) * 32];
  bf16_t* lbA = &Bs[0][(w * 16) * 32]; bf16_t* lbB = &Bs[1][(w * 16) * 32];

  const int po = (wr * 64 + c16) * 32 + g * 8;
  const int qo = (wc * 32 + c16) * 32 + g * 8;
  const bf16_t* paA = &As[0][po]; const bf16_t* paB = &As[1][po];
  const bf16_t* pbA = &Bs[0][qo]; const bf16_t* pbB = &Bs[1][qo];

  GLOAD_LDS16(ga, laA); GLOAD_LDS16(gb, lbA);
  __syncthreads();

  for (int it = 0; it < K / 32; ++it) {
    const bool odd = it & 1;
    const int kt = it * 32;
    if (kt + 32 < K) {
      GLOAD_LDS16(ga + kt + 32, odd ? laA : laB);
      GLOAD_LDS16(gb + kt + 32, odd ? lbA : lbB);
    }
    const bf16_t* pa = odd ? paB : paA;
    const bf16_t* pb = odd ? pbB : pbA;
    bf16x8 af[4], bfr[2];
    #pragma unroll
    for (int t = 0; t < 4; ++t) af[t]  = *(const bf16x8*)(pa + t * 16 * 32);
    #pragma unroll
    for (int t = 0; t < 2; ++t) bfr[t] = *(const bf16x8*)(pb + t * 16 * 32);
    #pragma unroll
    for (int i = 0; i < 4; ++i)
      #pragma unroll
      for (int j = 0; j < 2; ++j)
        acc[i][j] = mfma16(af[i], bfr[j], acc[i][j]);
    __syncthreads();
  }

  const int rbase = m0 + wr * 64 + (g << 2);
  const int cbase = n0 + wc * 32 + c16;
  #pragma unroll
  for (int j = 0; j < 2; ++j) {
    const int c = cbase + j * 16;
    const float bv = bias[c];
    #pragma unroll
    for (int i = 0; i < 4; ++i) {
      #pragma unroll
      for (int e = 0; e < 4; ++e) {
        const int r = rbase + i * 16 + e;
        C[(size_t)r * N + c] = acc[i][j][e] + bv;
      }
    }
  }
}

// ---------------- flash attention: sequential diagonal-pair blocks ----------------
// grid = 16 pairs x 32 bh = 512 blocks. Block pr processes q-tile pr THEN q-tile
// 31-pr (full r11 inner loop per pass). Trips = (pr+1)+(32-pr) = 33 for EVERY
// block -> uniform makespan, no within-CU tail (r11's constant-sum mapping had
// ~52% duty because resident blocks run concurrently and makespan = max, not sum).
// 2 blocks/CU x 4 waves, all busy until the end.
__global__ __launch_bounds__(256, 4) void k_attn(
    const bf16_t* __restrict__ Q, const bf16_t* __restrict__ K,
    const bf16_t* __restrict__ Vt, bf16_t* __restrict__ O)
{
  __shared__ __align__(16) bf16_t kbuf[2][64 * 64];
  __shared__ __align__(16) bf16_t vbuf[2][64 * 64];
  const int tid = threadIdx.x, lane = tid & 63, w = tid >> 6;
  const int pr = blockIdx.x >> 5;          // 0..15
  const int bh = blockIdx.x & 31;
  const int b  = bh >> 4, h = bh & 15;
  const int c16 = lane & 15;
  const int g   = lane >> 4;

  const bf16_t* Qb = Q  + (size_t)bh * SEQ * HD;
  const bf16_t* Kb = K  + (size_t)bh * SEQ * HD;
  const bf16_t* Vb = Vt + (size_t)bh * HD * SEQ;

  // ---- hoisted staging/read constants (pass-independent) ----
  const int soff0 = w * 1024 + lane * 16;
  const int soff1 = soff0 + 4096;
  const int srow0 = soff0 >> 7, srow1 = soff1 >> 7;
  const int scb0  = (soff0 & 127) ^ ((srow0 & 7) << 4);
  const int scb1  = (soff1 & 127) ^ ((srow1 & 7) << 4);
  const bf16_t* gkb0 = &Kb[(size_t)srow0 * HD + (scb0 >> 1)];
  const bf16_t* gkb1 = &Kb[(size_t)srow1 * HD + (scb1 >> 1)];
  const bf16_t* gvb0 = &Vb[(size_t)srow0 * SEQ + (scb0 >> 1)];
  const bf16_t* gvb1 = &Vb[(size_t)srow1 * SEQ + (scb1 >> 1)];
  bf16_t* lk0A = &kbuf[0][(w * 1024) >> 1];
  bf16_t* lk1A = &kbuf[0][(w * 1024 + 4096) >> 1];
  bf16_t* lk0B = &kbuf[1][(w * 1024) >> 1];
  bf16_t* lk1B = &kbuf[1][(w * 1024 + 4096) >> 1];
  bf16_t* lv0A = &vbuf[0][(w * 1024) >> 1];
  bf16_t* lv1A = &vbuf[0][(w * 1024 + 4096) >> 1];
  bf16_t* lv0B = &vbuf[1][(w * 1024) >> 1];
  bf16_t* lv1B = &vbuf[1][(w * 1024 + 4096) >> 1];

  const int sw = (c16 & 7) << 4;
  const int e0 = ((16 * g) ^ sw) >> 1;
  const int dhi = (((64 + 16 * g) ^ sw) >> 1) - e0;
  const bf16_t* kp0 = &kbuf[0][c16 * 64 + e0];
  const bf16_t* kp1 = &kbuf[1][c16 * 64 + e0];
  const bf16_t* vp0 = &vbuf[0][c16 * 64 + e0];
  const bf16_t* vp1 = &vbuf[1][c16 * 64 + e0];

  for (int pass = 0; pass < 2; ++pass) {
    const int qt = pass ? 31 - pr : pr;
    const int q0 = qt * 64 + w * 16;
    const int q  = q0 + c16;

    bf16x8 qf0 = *(const bf16x8*)&Qb[(size_t)q * HD + g * 8];
    bf16x8 qf1 = *(const bf16x8*)&Qb[(size_t)q * HD + 32 + g * 8];

    f32x4 oacc[4];
    #pragma unroll
    for (int dblk = 0; dblk < 4; ++dblk)
      #pragma unroll
      for (int e = 0; e < 4; ++e) oacc[dblk][e] = 0.0f;
    float m_ = -1e30f, l_ = 0.0f;

    const int ntile = qt + 1;
    const bf16_t* gk0 = gkb0;
    const bf16_t* gk1 = gkb1;
    const bf16_t* gv0 = gvb0;
    const bf16_t* gv1 = gvb1;

    GLOAD_LDS16(gk0, lk0A); GLOAD_LDS16(gk1, lk1A);
    GLOAD_LDS16(gv0, lv0A); GLOAD_LDS16(gv1, lv1A);
    gk0 += 4096; gk1 += 4096; gv0 += 64; gv1 += 64;
    __syncthreads();

    for (int t = 0; t < ntile; ++t) {
      const bool odd = t & 1;
      if (t + 1 < ntile) {
        GLOAD_LDS16(gk0, odd ? lk0A : lk0B); GLOAD_LDS16(gk1, odd ? lk1A : lk1B);
        GLOAD_LDS16(gv0, odd ? lv0A : lv0B); GLOAD_LDS16(gv1, odd ? lv1A : lv1B);
        gk0 += 4096; gk1 += 4096; gv0 += 64; gv1 += 64;
      }

      const bf16_t* kp = odd ? kp1 : kp0;
      const bf16_t* vp = odd ? vp1 : vp0;

      f32x4 st[4];
      __builtin_amdgcn_s_setprio(1);
      #pragma unroll
      for (int u = 0; u < 4; ++u) {
        bf16x8 k0 = *(const bf16x8*)(kp + u * 1024);
        bf16x8 k1 = *(const bf16x8*)(kp + u * 1024 + dhi);
        f32x4 z; z[0] = z[1] = z[2] = z[3] = 0.0f;
        z = mfma16(k0, qf0, z);
        z = mfma16(k1, qf1, z);
        st[u] = z;
      }
      __builtin_amdgcn_s_setprio(0);

      // ---- V fragments: b128 swizzled reads (permuted layout), same as K ----
      bf16x8 vlo[4], vhi[4];
      #pragma unroll
      for (int dblk = 0; dblk < 4; ++dblk) {
        vlo[dblk] = *(const bf16x8*)(vp + dblk * 1024);
        vhi[dblk] = *(const bf16x8*)(vp + dblk * 1024 + dhi);
      }

      float pv[16];
      if (t == qt) {
        const int kv0 = t * 64;
        #pragma unroll
        for (int u = 0; u < 4; ++u)
          #pragma unroll
          for (int r = 0; r < 4; ++r) {
            const int kv = kv0 + 16 * u + 4 * g + r;
            pv[u * 4 + r] = (kv <= q) ? st[u][r] : -1e30f;
          }
      } else {
        #pragma unroll
        for (int u = 0; u < 4; ++u)
          #pragma unroll
          for (int r = 0; r < 4; ++r)
            pv[u * 4 + r] = st[u][r];
      }

      // ---- local 16-max only (no cross-lane in common path) ----
      float ma = fmaxf(fmaxf(pv[0], pv[1]), fmaxf(pv[2], pv[3]));
      float mb = fmaxf(fmaxf(pv[4], pv[5]), fmaxf(pv[6], pv[7]));
      float mc = fmaxf(fmaxf(pv[8], pv[9]), fmaxf(pv[10], pv[11]));
      float md = fmaxf(fmaxf(pv[12], pv[13]), fmaxf(pv[14], pv[15]));
      const float lmx = fmaxf(fmaxf(ma, mb), fmaxf(mc, md));

      if (__any(lmx - m_ > 12.0f)) {
        float mx = fmaxf(lmx, __shfl_xor(lmx, 16));
        mx = fmaxf(mx, __shfl_xor(mx, 32));
        const float mn = fmaxf(m_, mx);
        const float alpha = exp2f(m_ - mn);
        l_ *= alpha;
        #pragma unroll
        for (int dblk = 0; dblk < 4; ++dblk)
          #pragma unroll
          for (int e = 0; e < 4; ++e) oacc[dblk][e] *= alpha;
        m_ = mn;
      }

      #pragma unroll
      for (int i = 0; i < 16; ++i) pv[i] = exp2f(pv[i] - m_);
      float s0 = (pv[0] + pv[1]) + (pv[2] + pv[3]);
      float s1 = (pv[4] + pv[5]) + (pv[6] + pv[7]);
      float s2 = (pv[8] + pv[9]) + (pv[10] + pv[11]);
      float s3 = (pv[12] + pv[13]) + (pv[14] + pv[15]);
      l_ += (s0 + s1) + (s2 + s3);

      bf16x8 pf0, pf1;
      #pragma unroll
      for (int j = 0; j < 8; ++j) {
        pf0[j] = (bf16_t)pv[j];
        pf1[j] = (bf16_t)pv[8 + j];
      }

      __builtin_amdgcn_s_setprio(1);
      #pragma unroll
      for (int dblk = 0; dblk < 4; ++dblk) {
        oacc[dblk] = mfma16(vlo[dblk], pf0, oacc[dblk]);
        oacc[dblk] = mfma16(vhi[dblk], pf1, oacc[dblk]);
      }
      __builtin_amdgcn_s_setprio(0);

      __syncthreads();
    }

    // ---- epilogue for this pass ----
    l_ += __shfl_xor(l_, 16);
    l_ += __shfl_xor(l_, 32);
    const float inv = 1.0f / l_;
    bf16_t* orow = O + ((size_t)(b * SEQ + q)) * DM + h * HD;
    #pragma unroll
    for (int dblk = 0; dblk < 4; ++dblk) {
      bf16x4 ov;
      #pragma unroll
      for (int r = 0; r < 4; ++r) ov[r] = (bf16_t)(oacc[dblk][r] * inv);
      *(bf16x4*)&orow[dblk * 16 + 4 * g] = ov;
    }
  }
}

// ---------------- launch ----------------
extern "C" void kernel_launch(void* const* d_in, const int* in_sizes, int n_in,
                              void* d_out, int out_size, void* d_ws, size_t ws_size,
                              hipStream_t stream)
{
  const float* x  = (const float*)d_in[0];
  const float* Wq = (const float*)d_in[1];
  const float* bq = (const float*)d_in[2];
  const float* Wk = (const float*)d_in[3];
  const float* bk = (const float*)d_in[4];
  const float* Wv = (const float*)d_in[5];
  const float* bv = (const float*)d_in[6];
  const float* Wo = (const float*)d_in[7];
  const float* bo = (const float*)d_in[8];
  float* out = (float*)d_out;

  char* ws = (char*)d_ws;
  size_t off = 0;
  auto alloc = [&](size_t bytes) { char* p = ws + off; off += (bytes + 255) & ~255ULL; return p; };
  bf16_t* xb   = (bf16_t*)alloc((size_t)BS * DM * 2);
  bf16_t* Wcat = (bf16_t*)alloc((size_t)NQKV * DM * 2);
  bf16_t* Wob  = (bf16_t*)alloc((size_t)DM * DM * 2);
  float*  bcat = (float*)alloc((size_t)NQKV * 4);
  float2* rt   = (float2*)alloc((size_t)SEQ * 32 * 8);
  bf16_t* Qh   = (bf16_t*)alloc((size_t)BS * DM * 2);
  bf16_t* Kh   = (bf16_t*)alloc((size_t)BS * DM * 2);
  bf16_t* Vth  = (bf16_t*)alloc((size_t)BS * DM * 2);
  bf16_t* Oh   = (bf16_t*)alloc((size_t)BS * DM * 2);
  (void)ws_size; (void)in_sizes; (void)n_in; (void)out_size;

  k_cast_all<<<4099 + 256, 256, 0, stream>>>(x, Wq, Wk, Wv, Wo, bq, bk, bv,
                                             xb, Wcat, Wob, bcat, rt);

  dim3 gqk(16, 32);
  k_gemm_qk<<<gqk, 256, 0, stream>>>(xb, Wcat, bcat, rt, Qh, Kh);
  dim3 gv(8, 32);
  k_gemm_v<<<gv, 256, 0, stream>>>(xb, Wcat + 2 * DM * DM, bcat + 2 * DM, Vth);
  k_attn<<<512, 256, 0, stream>>>(Qh, Kh, Vth, Oh);
  dim3 g2(DM / 128, BS / 128);
  k_gemm_out<<<g2, 512, 0, stream>>>(Oh, Wob, bo, out);
}

// Round 17
// 121.293 us; speedup vs baseline: 1.2749x; 1.0014x over previous
//
#include <hip/hip_runtime.h>
#include <hip/hip_bf16.h>
#include <stdint.h>

typedef __bf16 bf16_t;
typedef __bf16 bf16x4 __attribute__((ext_vector_type(4)));
typedef __bf16 bf16x8 __attribute__((ext_vector_type(8)));
typedef float  f32x4  __attribute__((ext_vector_type(4)));

#define DM    1024
#define NH    16
#define HD    64
#define SEQ   2048
#define BATCH 2
#define BS    (BATCH*SEQ)   // 4096
#define NQKV  (3*DM)        // 3072

#define GLOAD_LDS16(g, l) \
  __builtin_amdgcn_global_load_lds((const __attribute__((address_space(1))) void*)(g), \
                                   (__attribute__((address_space(3))) void*)(l), 16, 0, 0)

__device__ __forceinline__ f32x4 mfma16(bf16x8 a, bf16x8 b, f32x4 c) {
  return __builtin_amdgcn_mfma_f32_16x16x32_bf16(a, b, c, 0, 0, 0);
}

// ---------------- merged cast/copy + rope-table kernel ----------------
__global__ __launch_bounds__(256) void k_cast_all(
    const float* __restrict__ x,  const float* __restrict__ Wq,
    const float* __restrict__ Wk, const float* __restrict__ Wv,
    const float* __restrict__ Wo, const float* __restrict__ bq,
    const float* __restrict__ bk, const float* __restrict__ bv,
    bf16_t* __restrict__ xb, bf16_t* __restrict__ Wcat,
    bf16_t* __restrict__ Wob, float* __restrict__ bcat,
    float2* __restrict__ rt)
{
  const int bid = blockIdx.x, tid = threadIdx.x;
  if (bid >= 4099) {
    const int idx = (bid - 4099) * 256 + tid;   // SEQ*32 = 65536 entries
    const int s = idx >> 5, i = idx & 31;
    float inv = powf(10000.0f, -(float)(2 * i) / 64.0f);
    float ang = (float)s * inv;
    rt[idx] = make_float2(cosf(ang), sinf(ang));
    return;
  }
  if (bid >= 4096) {
    const int k = bid - 4096;
    const float* src = (k == 0) ? bq : (k == 1) ? bk : bv;
    *(float4*)&bcat[k * DM + tid * 4] = *(const float4*)&src[tid * 4];
    return;
  }
  const float* src; bf16_t* dst; int i;
  if (bid < 2048)      { src = x;  dst = xb;                i = bid * 2048 + tid * 8; }
  else if (bid < 2560) { src = Wq; dst = Wcat;              i = (bid - 2048) * 2048 + tid * 8; }
  else if (bid < 3072) { src = Wk; dst = Wcat + DM * DM;    i = (bid - 2560) * 2048 + tid * 8; }
  else if (bid < 3584) { src = Wv; dst = Wcat + 2 * DM * DM;i = (bid - 3072) * 2048 + tid * 8; }
  else                 { src = Wo; dst = Wob;               i = (bid - 3584) * 2048 + tid * 8; }
  float4 a = *(const float4*)(src + i);
  float4 b = *(const float4*)(src + i + 4);
  bf16x8 o;
  o[0] = (bf16_t)a.x; o[1] = (bf16_t)a.y; o[2] = (bf16_t)a.z; o[3] = (bf16_t)a.w;
  o[4] = (bf16_t)b.x; o[5] = (bf16_t)b.y; o[6] = (bf16_t)b.z; o[7] = (bf16_t)b.w;
  *(bf16x8*)(dst + i) = o;
}

// ---------------- Q/K projection GEMM (C^T) + bias + RoPE, LDS double-buffered ---
__global__ __launch_bounds__(256) void k_gemm_qk(
    const bf16_t* __restrict__ A, const bf16_t* __restrict__ B,
    const float* __restrict__ bias, const float2* __restrict__ rt,
    bf16_t* __restrict__ Qo, bf16_t* __restrict__ Ko)
{
  const int K = DM;
  __shared__ __align__(16) bf16_t As[2][128 * 32];
  __shared__ __align__(16) bf16_t Bs[2][128 * 32];
  const int tid  = threadIdx.x;
  const int lane = tid & 63;
  const int wave = tid >> 6;
  const int wr = wave >> 1, wc = wave & 1;
  const int m0 = blockIdx.y * 128, n0 = blockIdx.x * 128;
  const int c16 = lane & 15, g = lane >> 4;

  f32x4 acc[4][4];
  #pragma unroll
  for (int i = 0; i < 4; ++i)
    #pragma unroll
    for (int j = 0; j < 4; ++j)
      #pragma unroll
      for (int e = 0; e < 4; ++e) acc[i][j][e] = 0.0f;

  const int srow = wave * 32;
  const int lrow = lane >> 2;
  const int lk   = (lane & 3) * 8;
  const bf16_t* ga0 = A + (size_t)(m0 + srow +      lrow) * K + lk;
  const bf16_t* ga1 = A + (size_t)(m0 + srow + 16 + lrow) * K + lk;
  const bf16_t* gb0 = B + (size_t)(n0 + srow +      lrow) * K + lk;
  const bf16_t* gb1 = B + (size_t)(n0 + srow + 16 + lrow) * K + lk;
  bf16_t* la0A = &As[0][(srow) * 32];      bf16_t* la0B = &As[1][(srow) * 32];
  bf16_t* la1A = &As[0][(srow + 16) * 32]; bf16_t* la1B = &As[1][(srow + 16) * 32];
  bf16_t* lb0A = &Bs[0][(srow) * 32];      bf16_t* lb0B = &Bs[1][(srow) * 32];
  bf16_t* lb1A = &Bs[0][(srow + 16) * 32]; bf16_t* lb1B = &Bs[1][(srow + 16) * 32];

  const int po = (wr * 64 + c16) * 32 + g * 8;
  const int qo = (wc * 64 + c16) * 32 + g * 8;
  const bf16_t* paA = &As[0][po]; const bf16_t* paB = &As[1][po];
  const bf16_t* pbA = &Bs[0][qo]; const bf16_t* pbB = &Bs[1][qo];

  GLOAD_LDS16(ga0, la0A); GLOAD_LDS16(ga1, la1A);
  GLOAD_LDS16(gb0, lb0A); GLOAD_LDS16(gb1, lb1A);
  __syncthreads();

  for (int it = 0; it < K / 32; ++it) {
    const bool odd = it & 1;
    const int kt = it * 32;
    if (kt + 32 < K) {
      GLOAD_LDS16(ga0 + kt + 32, odd ? la0A : la0B);
      GLOAD_LDS16(ga1 + kt + 32, odd ? la1A : la1B);
      GLOAD_LDS16(gb0 + kt + 32, odd ? lb0A : lb0B);
      GLOAD_LDS16(gb1 + kt + 32, odd ? lb1A : lb1B);
    }
    const bf16_t* pa = odd ? paB : paA;
    const bf16_t* pb = odd ? pbB : pbA;
    bf16x8 af[4], bfr[4];
    #pragma unroll
    for (int t = 0; t < 4; ++t) af[t]  = *(const bf16x8*)(pa + t * 16 * 32);
    #pragma unroll
    for (int t = 0; t < 4; ++t) bfr[t] = *(const bf16x8*)(pb + t * 16 * 32);
    #pragma unroll
    for (int i = 0; i < 4; ++i)
      #pragma unroll
      for (int j = 0; j < 4; ++j)
        acc[i][j] = mfma16(bfr[j], af[i], acc[i][j]);   // SWAPPED -> C^T layout
    __syncthreads();
  }

  const int region = n0 >> 10;                 // 0=Q, 1=K
  bf16_t* dst = region ? Ko : Qo;
  const float qs = region ? 1.0f : (0.125f * 1.44269504088896f);
  #pragma unroll
  for (int j = 0; j < 4; ++j) {
    const int nb = n0 + wc * 64 + j * 16 + (g << 2);   // n of e=0
    const float4 bv = *(const float4*)&bias[nb];
    const int h  = (nb >> 6) & 15;
    const int d0 = nb & 63;
    #pragma unroll
    for (int i = 0; i < 4; ++i) {
      const int m = m0 + wr * 64 + i * 16 + c16;
      const int s = m & 2047;
      const int bh = ((m >> 11) << 4) + h;
      const float4 cs = *(const float4*)&rt[(size_t)s * 32 + (d0 >> 1)];
      const float v0 = acc[i][j][0] + bv.x;
      const float v1 = acc[i][j][1] + bv.y;
      const float v2 = acc[i][j][2] + bv.z;
      const float v3 = acc[i][j][3] + bv.w;
      bf16x4 ov;
      ov[0] = (bf16_t)((v0 * cs.x - v1 * cs.y) * qs);
      ov[1] = (bf16_t)((v0 * cs.y + v1 * cs.x) * qs);
      ov[2] = (bf16_t)((v2 * cs.z - v3 * cs.w) * qs);
      ov[3] = (bf16_t)((v2 * cs.w + v3 * cs.z) * qs);
      *(bf16x4*)&dst[((size_t)bh * SEQ + s) * HD + d0] = ov;
    }
  }
}

// ---------------- V projection GEMM + bias + PERMUTED V^T, LDS double-buffered ---
__global__ __launch_bounds__(256) void k_gemm_v(
    const bf16_t* __restrict__ A, const bf16_t* __restrict__ B,
    const float* __restrict__ bias, bf16_t* __restrict__ Vt)
{
  const int K = DM;
  __shared__ __align__(16) bf16_t As[2][128 * 32];
  __shared__ __align__(16) bf16_t Bs[2][128 * 32];
  const int tid  = threadIdx.x;
  const int lane = tid & 63;
  const int wave = tid >> 6;
  const int wr = wave >> 1, wc = wave & 1;
  const int m0 = blockIdx.y * 128, n0 = blockIdx.x * 128;
  const int c16 = lane & 15, g = lane >> 4;

  f32x4 acc[4][4];
  #pragma unroll
  for (int i = 0; i < 4; ++i)
    #pragma unroll
    for (int j = 0; j < 4; ++j)
      #pragma unroll
      for (int e = 0; e < 4; ++e) acc[i][j][e] = 0.0f;

  const int srow = wave * 32;
  const int lrow = lane >> 2;
  const int lk   = (lane & 3) * 8;
  const bf16_t* ga0 = A + (size_t)(m0 + srow +      lrow) * K + lk;
  const bf16_t* ga1 = A + (size_t)(m0 + srow + 16 + lrow) * K + lk;
  const bf16_t* gb0 = B + (size_t)(n0 + srow +      lrow) * K + lk;
  const bf16_t* gb1 = B + (size_t)(n0 + srow + 16 + lrow) * K + lk;
  bf16_t* la0A = &As[0][(srow) * 32];      bf16_t* la0B = &As[1][(srow) * 32];
  bf16_t* la1A = &As[0][(srow + 16) * 32]; bf16_t* la1B = &As[1][(srow + 16) * 32];
  bf16_t* lb0A = &Bs[0][(srow) * 32];      bf16_t* lb0B = &Bs[1][(srow) * 32];
  bf16_t* lb1A = &Bs[0][(srow + 16) * 32]; bf16_t* lb1B = &Bs[1][(srow + 16) * 32];

  const int po = (wr * 64 + c16) * 32 + g * 8;
  const int qo = (wc * 64 + c16) * 32 + g * 8;
  const bf16_t* paA = &As[0][po]; const bf16_t* paB = &As[1][po];
  const bf16_t* pbA = &Bs[0][qo]; const bf16_t* pbB = &Bs[1][qo];

  GLOAD_LDS16(ga0, la0A); GLOAD_LDS16(ga1, la1A);
  GLOAD_LDS16(gb0, lb0A); GLOAD_LDS16(gb1, lb1A);
  __syncthreads();

  for (int it = 0; it < K / 32; ++it) {
    const bool odd = it & 1;
    const int kt = it * 32;
    if (kt + 32 < K) {
      GLOAD_LDS16(ga0 + kt + 32, odd ? la0A : la0B);
      GLOAD_LDS16(ga1 + kt + 32, odd ? la1A : la1B);
      GLOAD_LDS16(gb0 + kt + 32, odd ? lb0A : lb0B);
      GLOAD_LDS16(gb1 + kt + 32, odd ? lb1A : lb1B);
    }
    const bf16_t* pa = odd ? paB : paA;
    const bf16_t* pb = odd ? pbB : pbA;
    bf16x8 af[4], bfr[4];
    #pragma unroll
    for (int t = 0; t < 4; ++t) af[t]  = *(const bf16x8*)(pa + t * 16 * 32);
    #pragma unroll
    for (int t = 0; t < 4; ++t) bfr[t] = *(const bf16x8*)(pb + t * 16 * 32);
    #pragma unroll
    for (int i = 0; i < 4; ++i)
      #pragma unroll
      for (int j = 0; j < 4; ++j)
        acc[i][j] = mfma16(af[i], bfr[j], acc[i][j]);
    __syncthreads();
  }

  const int rbase = m0 + wr * 64 + (g << 2);
  const int cbase = n0 + wc * 64 + c16;
  #pragma unroll
  for (int j = 0; j < 4; ++j) {
    const int c = cbase + j * 16;
    const float bv = bias[c];
    const int h = (c >> 6) & 15;
    const int d = c & 63;
    #pragma unroll
    for (int i = 0; i < 4; ++i) {
      bf16x4 ov;
      #pragma unroll
      for (int e = 0; e < 4; ++e) ov[e] = (bf16_t)(acc[i][j][e] + bv);
      const int r0 = rbase + i * 16;
      const int bh = ((r0 >> 11) << 4) + h;
      const int s0 = r0 & 2047;
      const int u  = (s0 >> 4) & 3;
      const int p0 = (s0 & ~63) + ((u >> 1) << 5) + (g << 3) + ((u & 1) << 2);
      *(bf16x4*)&Vt[((size_t)bh * HD + d) * SEQ + p0] = ov;
    }
  }
}

// ---------------- output projection GEMM: 8 waves, LDS double-buffered ----------
__global__ __launch_bounds__(512) void k_gemm_out(
    const bf16_t* __restrict__ A, const bf16_t* __restrict__ B,
    const float* __restrict__ bias, float* __restrict__ C)
{
  const int K = DM, N = DM;
  __shared__ __align__(16) bf16_t As[2][128 * 32];
  __shared__ __align__(16) bf16_t Bs[2][128 * 32];
  const int tid  = threadIdx.x;
  const int lane = tid & 63;
  const int w    = tid >> 6;
  const int wr = w >> 2, wc = w & 3;
  const int m0 = blockIdx.y * 128, n0 = blockIdx.x * 128;
  const int c16 = lane & 15, g = lane >> 4;

  f32x4 acc[4][2];
  #pragma unroll
  for (int i = 0; i < 4; ++i)
    #pragma unroll
    for (int j = 0; j < 2; ++j)
      #pragma unroll
      for (int e = 0; e < 4; ++e) acc[i][j][e] = 0.0f;

  const int lrow = lane >> 2;
  const int lk   = (lane & 3) * 8;
  const bf16_t* ga = A + (size_t)(m0 + w * 16 + lrow) * K + lk;
  const bf16_t* gb = B + (size_t)(n0 + w * 16 + lrow) * K + lk;
  bf16_t* laA = &As[0][(w * 16) * 32]; bf16_t* laB = &As[1][(w * 16) * 32];
  bf16_t* lbA = &Bs[0][(w * 16) * 32]; bf16_t* lbB = &Bs[1][(w * 16) * 32];

  const int po = (wr * 64 + c16) * 32 + g * 8;
  const int qo = (wc * 32 + c16) * 32 + g * 8;
  const bf16_t* paA = &As[0][po]; const bf16_t* paB = &As[1][po];
  const bf16_t* pbA = &Bs[0][qo]; const bf16_t* pbB = &Bs[1][qo];

  GLOAD_LDS16(ga, laA); GLOAD_LDS16(gb, lbA);
  __syncthreads();

  for (int it = 0; it < K / 32; ++it) {
    const bool odd = it & 1;
    const int kt = it * 32;
    if (kt + 32 < K) {
      GLOAD_LDS16(ga + kt + 32, odd ? laA : laB);
      GLOAD_LDS16(gb + kt + 32, odd ? lbA : lbB);
    }
    const bf16_t* pa = odd ? paB : paA;
    const bf16_t* pb = odd ? pbB : pbA;
    bf16x8 af[4], bfr[2];
    #pragma unroll
    for (int t = 0; t < 4; ++t) af[t]  = *(const bf16x8*)(pa + t * 16 * 32);
    #pragma unroll
    for (int t = 0; t < 2; ++t) bfr[t] = *(const bf16x8*)(pb + t * 16 * 32);
    #pragma unroll
    for (int i = 0; i < 4; ++i)
      #pragma unroll
      for (int j = 0; j < 2; ++j)
        acc[i][j] = mfma16(af[i], bfr[j], acc[i][j]);
    __syncthreads();
  }

  const int rbase = m0 + wr * 64 + (g << 2);
  const int cbase = n0 + wc * 32 + c16;
  #pragma unroll
  for (int j = 0; j < 2; ++j) {
    const int c = cbase + j * 16;
    const float bv = bias[c];
    #pragma unroll
    for (int i = 0; i < 4; ++i) {
      #pragma unroll
      for (int e = 0; e < 4; ++e) {
        const int r = rbase + i * 16 + e;
        C[(size_t)r * N + c] = acc[i][j][e] + bv;
      }
    }
  }
}

// ---------------- flash attention: fused diagonal-pair, shared K/V staging -------
// grid = 16 pairs x 32 bh = 512 blocks. Block pr owns q-tiles A=pr and B=31-pr,
// processed IN THE SAME tile loop sharing staged K/V: staged tiles = 32-pr (vs 33
// when sequential), and dual-active tiles put 32 MFMAs + 2 independent softmax
// chains between barriers (fills the staging-latency hole that TLP can't: r16
// showed halving blocks/CU didn't change dur). A-side predicate t<=pr is block-
// uniform. K/V fragments re-read from LDS for the second q-tile (conflict-free).
__global__ __launch_bounds__(256, 2) void k_attn(
    const bf16_t* __restrict__ Q, const bf16_t* __restrict__ K,
    const bf16_t* __restrict__ Vt, bf16_t* __restrict__ O)
{
  __shared__ __align__(16) bf16_t kbuf[2][64 * 64];
  __shared__ __align__(16) bf16_t vbuf[2][64 * 64];
  const int tid = threadIdx.x, lane = tid & 63, w = tid >> 6;
  const int pr = blockIdx.x >> 5;          // 0..15
  const int bh = blockIdx.x & 31;
  const int b  = bh >> 4, h = bh & 15;
  const int c16 = lane & 15;
  const int g   = lane >> 4;

  const bf16_t* Qb = Q  + (size_t)bh * SEQ * HD;
  const bf16_t* Kb = K  + (size_t)bh * SEQ * HD;
  const bf16_t* Vb = Vt + (size_t)bh * HD * SEQ;

  const int qtA = pr, qtB = 31 - pr;
  const int qA  = qtA * 64 + w * 16 + c16;
  const int qB  = qtB * 64 + w * 16 + c16;
  const int Tmax = qtB + 1;                // 32 - pr staged tiles

  bf16x8 qfA0 = *(const bf16x8*)&Qb[(size_t)qA * HD + g * 8];
  bf16x8 qfA1 = *(const bf16x8*)&Qb[(size_t)qA * HD + 32 + g * 8];
  bf16x8 qfB0 = *(const bf16x8*)&Qb[(size_t)qB * HD + g * 8];
  bf16x8 qfB1 = *(const bf16x8*)&Qb[(size_t)qB * HD + 32 + g * 8];

  f32x4 oaccA[4], oaccB[4];
  #pragma unroll
  for (int dblk = 0; dblk < 4; ++dblk)
    #pragma unroll
    for (int e = 0; e < 4; ++e) { oaccA[dblk][e] = 0.0f; oaccB[dblk][e] = 0.0f; }
  float mA = -1e30f, lA = 0.0f, mB = -1e30f, lB = 0.0f;

  // ---- staging addresses (hoisted) ----
  const int soff0 = w * 1024 + lane * 16;
  const int soff1 = soff0 + 4096;
  const int srow0 = soff0 >> 7, srow1 = soff1 >> 7;
  const int scb0  = (soff0 & 127) ^ ((srow0 & 7) << 4);
  const int scb1  = (soff1 & 127) ^ ((srow1 & 7) << 4);
  const bf16_t* gk0 = &Kb[(size_t)srow0 * HD + (scb0 >> 1)];
  const bf16_t* gk1 = &Kb[(size_t)srow1 * HD + (scb1 >> 1)];
  const bf16_t* gv0 = &Vb[(size_t)srow0 * SEQ + (scb0 >> 1)];
  const bf16_t* gv1 = &Vb[(size_t)srow1 * SEQ + (scb1 >> 1)];
  bf16_t* lk0A = &kbuf[0][(w * 1024) >> 1];
  bf16_t* lk1A = &kbuf[0][(w * 1024 + 4096) >> 1];
  bf16_t* lk0B = &kbuf[1][(w * 1024) >> 1];
  bf16_t* lk1B = &kbuf[1][(w * 1024 + 4096) >> 1];
  bf16_t* lv0A = &vbuf[0][(w * 1024) >> 1];
  bf16_t* lv1A = &vbuf[0][(w * 1024 + 4096) >> 1];
  bf16_t* lv0B = &vbuf[1][(w * 1024) >> 1];
  bf16_t* lv1B = &vbuf[1][(w * 1024 + 4096) >> 1];

  const int sw = (c16 & 7) << 4;
  const int e0 = ((16 * g) ^ sw) >> 1;
  const int dhi = (((64 + 16 * g) ^ sw) >> 1) - e0;
  const bf16_t* kp0 = &kbuf[0][c16 * 64 + e0];
  const bf16_t* kp1 = &kbuf[1][c16 * 64 + e0];
  const bf16_t* vp0 = &vbuf[0][c16 * 64 + e0];
  const bf16_t* vp1 = &vbuf[1][c16 * 64 + e0];

  GLOAD_LDS16(gk0, lk0A); GLOAD_LDS16(gk1, lk1A);
  GLOAD_LDS16(gv0, lv0A); GLOAD_LDS16(gv1, lv1A);
  gk0 += 4096; gk1 += 4096; gv0 += 64; gv1 += 64;
  __syncthreads();

  for (int t = 0; t < Tmax; ++t) {
    const bool odd = t & 1;
    if (t + 1 < Tmax) {
      GLOAD_LDS16(gk0, odd ? lk0A : lk0B); GLOAD_LDS16(gk1, odd ? lk1A : lk1B);
      GLOAD_LDS16(gv0, odd ? lv0A : lv0B); GLOAD_LDS16(gv1, odd ? lv1A : lv1B);
      gk0 += 4096; gk1 += 4096; gv0 += 64; gv1 += 64;
    }

    const bf16_t* kp = odd ? kp1 : kp0;
    const bf16_t* vp = odd ? vp1 : vp0;

    // ================= B side (always active) =================
    {
      f32x4 st[4];
      __builtin_amdgcn_s_setprio(1);
      #pragma unroll
      for (int u = 0; u < 4; ++u) {
        bf16x8 k0 = *(const bf16x8*)(kp + u * 1024);
        bf16x8 k1 = *(const bf16x8*)(kp + u * 1024 + dhi);
        f32x4 z; z[0] = z[1] = z[2] = z[3] = 0.0f;
        z = mfma16(k0, qfB0, z);
        z = mfma16(k1, qfB1, z);
        st[u] = z;
      }
      __builtin_amdgcn_s_setprio(0);

      bf16x8 vlo[4], vhi[4];
      #pragma unroll
      for (int dblk = 0; dblk < 4; ++dblk) {
        vlo[dblk] = *(const bf16x8*)(vp + dblk * 1024);
        vhi[dblk] = *(const bf16x8*)(vp + dblk * 1024 + dhi);
      }

      float pv[16];
      if (t == qtB) {
        const int kv0 = t * 64;
        #pragma unroll
        for (int u = 0; u < 4; ++u)
          #pragma unroll
          for (int r = 0; r < 4; ++r) {
            const int kv = kv0 + 16 * u + 4 * g + r;
            pv[u * 4 + r] = (kv <= qB) ? st[u][r] : -1e30f;
          }
      } else {
        #pragma unroll
        for (int u = 0; u < 4; ++u)
          #pragma unroll
          for (int r = 0; r < 4; ++r)
            pv[u * 4 + r] = st[u][r];
      }

      float ma = fmaxf(fmaxf(pv[0], pv[1]), fmaxf(pv[2], pv[3]));
      float mb = fmaxf(fmaxf(pv[4], pv[5]), fmaxf(pv[6], pv[7]));
      float mc = fmaxf(fmaxf(pv[8], pv[9]), fmaxf(pv[10], pv[11]));
      float md = fmaxf(fmaxf(pv[12], pv[13]), fmaxf(pv[14], pv[15]));
      const float lmx = fmaxf(fmaxf(ma, mb), fmaxf(mc, md));

      if (__any(lmx - mB > 12.0f)) {
        float mx = fmaxf(lmx, __shfl_xor(lmx, 16));
        mx = fmaxf(mx, __shfl_xor(mx, 32));
        const float mn = fmaxf(mB, mx);
        const float alpha = exp2f(mB - mn);
        lB *= alpha;
        #pragma unroll
        for (int dblk = 0; dblk < 4; ++dblk)
          #pragma unroll
          for (int e = 0; e < 4; ++e) oaccB[dblk][e] *= alpha;
        mB = mn;
      }

      #pragma unroll
      for (int i = 0; i < 16; ++i) pv[i] = exp2f(pv[i] - mB);
      float s0 = (pv[0] + pv[1]) + (pv[2] + pv[3]);
      float s1 = (pv[4] + pv[5]) + (pv[6] + pv[7]);
      float s2 = (pv[8] + pv[9]) + (pv[10] + pv[11]);
      float s3 = (pv[12] + pv[13]) + (pv[14] + pv[15]);
      lB += (s0 + s1) + (s2 + s3);

      bf16x8 pf0, pf1;
      #pragma unroll
      for (int j = 0; j < 8; ++j) {
        pf0[j] = (bf16_t)pv[j];
        pf1[j] = (bf16_t)pv[8 + j];
      }

      __builtin_amdgcn_s_setprio(1);
      #pragma unroll
      for (int dblk = 0; dblk < 4; ++dblk) {
        oaccB[dblk] = mfma16(vlo[dblk], pf0, oaccB[dblk]);
        oaccB[dblk] = mfma16(vhi[dblk], pf1, oaccB[dblk]);
      }
      __builtin_amdgcn_s_setprio(0);
    }

    // ================= A side (active while t <= qtA; block-uniform) =========
    if (t <= qtA) {
      f32x4 st[4];
      __builtin_amdgcn_s_setprio(1);
      #pragma unroll
      for (int u = 0; u < 4; ++u) {
        bf16x8 k0 = *(const bf16x8*)(kp + u * 1024);
        bf16x8 k1 = *(const bf16x8*)(kp + u * 1024 + dhi);
        f32x4 z; z[0] = z[1] = z[2] = z[3] = 0.0f;
        z = mfma16(k0, qfA0, z);
        z = mfma16(k1, qfA1, z);
        st[u] = z;
      }
      __builtin_amdgcn_s_setprio(0);

      bf16x8 vlo[4], vhi[4];
      #pragma unroll
      for (int dblk = 0; dblk < 4; ++dblk) {
        vlo[dblk] = *(const bf16x8*)(vp + dblk * 1024);
        vhi[dblk] = *(const bf16x8*)(vp + dblk * 1024 + dhi);
      }

      float pv[16];
      if (t == qtA) {
        const int kv0 = t * 64;
        #pragma unroll
        for (int u = 0; u < 4; ++u)
          #pragma unroll
          for (int r = 0; r < 4; ++r) {
            const int kv = kv0 + 16 * u + 4 * g + r;
            pv[u * 4 + r] = (kv <= qA) ? st[u][r] : -1e30f;
          }
      } else {
        #pragma unroll
        for (int u = 0; u < 4; ++u)
          #pragma unroll
          for (int r = 0; r < 4; ++r)
            pv[u * 4 + r] = st[u][r];
      }

      float ma = fmaxf(fmaxf(pv[0], pv[1]), fmaxf(pv[2], pv[3]));
      float mb = fmaxf(fmaxf(pv[4], pv[5]), fmaxf(pv[6], pv[7]));
      float mc = fmaxf(fmaxf(pv[8], pv[9]), fmaxf(pv[10], pv[11]));
      float md = fmaxf(fmaxf(pv[12], pv[13]), fmaxf(pv[14], pv[15]));
      const float lmx = fmaxf(fmaxf(ma, mb), fmaxf(mc, md));

      if (__any(lmx - mA > 12.0f)) {
        float mx = fmaxf(lmx, __shfl_xor(lmx, 16));
        mx = fmaxf(mx, __shfl_xor(mx, 32));
        const float mn = fmaxf(mA, mx);
        const float alpha = exp2f(mA - mn);
        lA *= alpha;
        #pragma unroll
        for (int dblk = 0; dblk < 4; ++dblk)
          #pragma unroll
          for (int e = 0; e < 4; ++e) oaccA[dblk][e] *= alpha;
        mA = mn;
      }

      #pragma unroll
      for (int i = 0; i < 16; ++i) pv[i] = exp2f(pv[i] - mA);
      float s0 = (pv[0] + pv[1]) + (pv[2] + pv[3]);
      float s1 = (pv[4] + pv[5]) + (pv[6] + pv[7]);
      float s2 = (pv[8] + pv[9]) + (pv[10] + pv[11]);
      float s3 = (pv[12] + pv[13]) + (pv[14] + pv[15]);
      lA += (s0 + s1) + (s2 + s3);

      bf16x8 pf0, pf1;
      #pragma unroll
      for (int j = 0; j < 8; ++j) {
        pf0[j] = (bf16_t)pv[j];
        pf1[j] = (bf16_t)pv[8 + j];
      }

      __builtin_amdgcn_s_setprio(1);
      #pragma unroll
      for (int dblk = 0; dblk < 4; ++dblk) {
        oaccA[dblk] = mfma16(vlo[dblk], pf0, oaccA[dblk]);
        oaccA[dblk] = mfma16(vhi[dblk], pf1, oaccA[dblk]);
      }
      __builtin_amdgcn_s_setprio(0);
    }

    __syncthreads();
  }

  // ---- epilogues ----
  lA += __shfl_xor(lA, 16);
  lA += __shfl_xor(lA, 32);
  lB += __shfl_xor(lB, 16);
  lB += __shfl_xor(lB, 32);
  const float invA = 1.0f / lA;
  const float invB = 1.0f / lB;
  bf16_t* orowA = O + ((size_t)(b * SEQ + qA)) * DM + h * HD;
  bf16_t* orowB = O + ((size_t)(b * SEQ + qB)) * DM + h * HD;
  #pragma unroll
  for (int dblk = 0; dblk < 4; ++dblk) {
    bf16x4 ovA, ovB;
    #pragma unroll
    for (int r = 0; r < 4; ++r) {
      ovA[r] = (bf16_t)(oaccA[dblk][r] * invA);
      ovB[r] = (bf16_t)(oaccB[dblk][r] * invB);
    }
    *(bf16x4*)&orowA[dblk * 16 + 4 * g] = ovA;
    *(bf16x4*)&orowB[dblk * 16 + 4 * g] = ovB;
  }
}

// ---------------- launch ----------------
extern "C" void kernel_launch(void* const* d_in, const int* in_sizes, int n_in,
                              void* d_out, int out_size, void* d_ws, size_t ws_size,
                              hipStream_t stream)
{
  const float* x  = (const float*)d_in[0];
  const float* Wq = (const float*)d_in[1];
  const float* bq = (const float*)d_in[2];
  const float* Wk = (const float*)d_in[3];
  const float* bk = (const float*)d_in[4];
  const float* Wv = (const float*)d_in[5];
  const float* bv = (const float*)d_in[6];
  const float* Wo = (const float*)d_in[7];
  const float* bo = (const float*)d_in[8];
  float* out = (float*)d_out;

  char* ws = (char*)d_ws;
  size_t off = 0;
  auto alloc = [&](size_t bytes) { char* p = ws + off; off += (bytes + 255) & ~255ULL; return p; };
  bf16_t* xb   = (bf16_t*)alloc((size_t)BS * DM * 2);
  bf16_t* Wcat = (bf16_t*)alloc((size_t)NQKV * DM * 2);
  bf16_t* Wob  = (bf16_t*)alloc((size_t)DM * DM * 2);
  float*  bcat = (float*)alloc((size_t)NQKV * 4);
  float2* rt   = (float2*)alloc((size_t)SEQ * 32 * 8);
  bf16_t* Qh   = (bf16_t*)alloc((size_t)BS * DM * 2);
  bf16_t* Kh   = (bf16_t*)alloc((size_t)BS * DM * 2);
  bf16_t* Vth  = (bf16_t*)alloc((size_t)BS * DM * 2);
  bf16_t* Oh   = (bf16_t*)alloc((size_t)BS * DM * 2);
  (void)ws_size; (void)in_sizes; (void)n_in; (void)out_size;

  k_cast_all<<<4099 + 256, 256, 0, stream>>>(x, Wq, Wk, Wv, Wo, bq, bk, bv,
                                             xb, Wcat, Wob, bcat, rt);

  dim3 gqk(16, 32);
  k_gemm_qk<<<gqk, 256, 0, stream>>>(xb, Wcat, bcat, rt, Qh, Kh);
  dim3 gv(8, 32);
  k_gemm_v<<<gv, 256, 0, stream>>>(xb, Wcat + 2 * DM * DM, bcat + 2 * DM, Vth);
  k_attn<<<512, 256, 0, stream>>>(Qh, Kh, Vth, Oh);
  dim3 g2(DM / 128, BS / 128);
  k_gemm_out<<<g2, 512, 0, stream>>>(Oh, Wob, bo, out);
}